// Round 19
// baseline (226.885 us; speedup 1.0000x reference)
//
#include <hip/hip_runtime.h>
#include <math.h>

// B=16, L=512, D_MODEL=512, H=8, M=2, E=64, KMA=25, KLAM=7
// Outputs (f32, concat): out (16,512,512) | attn (16,8,512,512) | om_pen | th_pen
// Single-bf16 arithmetic everywhere.

#define PI_F 3.14159265358979323846f

typedef __attribute__((ext_vector_type(8))) short bf16x8;
typedef __attribute__((ext_vector_type(4))) float f32x4;

static constexpr long ATTN_OFF = 4194304;
static constexpr long OM_OFF   = 37748736;
static constexpr long TH_OFF   = 37748737;

// ---------------------------------------------------------------------------
__device__ __forceinline__ ushort f2bf(float f){
  uint u = __float_as_uint(f);
  u += 0x7fffu + ((u >> 16) & 1u);
  return (ushort)(u >> 16);
}
__device__ __forceinline__ float bf2f(ushort h){
  return __uint_as_float((uint)h << 16);
}
__device__ __forceinline__ uint4 cvt8s(const float* f){
  ushort h[8];
#pragma unroll
  for (int j = 0; j < 8; j++) h[j] = f2bf(f[j]);
  uint4 H;
  H.x = (uint)h[0] | ((uint)h[1] << 16); H.y = (uint)h[2] | ((uint)h[3] << 16);
  H.z = (uint)h[4] | ((uint)h[5] << 16); H.w = (uint)h[6] | ((uint)h[7] << 16);
  return H;
}

// ---------------------------------------------------------------------------
// Single-stream async LDS staging: dest lane-linear (p*16B), swizzle moved to
// global source via involution kb = (p&7)^(row&7)  (rule #21).
// ---------------------------------------------------------------------------
template<int ROWS>
__device__ __forceinline__ void stage_sb(const short* __restrict__ G, int ldk,
                                         short* dst, int t){
#pragma unroll
  for (int i = 0; i < ROWS*8/256; i++){
    int p = t + i*256;
    int row = p >> 3;
    int kb = (p & 7) ^ (row & 7);
    __builtin_amdgcn_global_load_lds(
        (const __attribute__((address_space(1))) uint*)(G + (long)row*ldk + kb*8),
        (__attribute__((address_space(3))) uint*)(dst + (long)p*8), 16, 0, 0);
  }
}

// sync single-stream stage (register round-trip) — flash Q
template<int ROWS>
__device__ __forceinline__ void stage_sync(const short* __restrict__ G, int ldk,
                                           short* dst, int t){
#pragma unroll
  for (int i = 0; i < ROWS*8/256; i++){
    int p = t + i*256;
    int row = p >> 3, kb = p & 7;
    uint4 v = *(const uint4*)(G + (long)row*ldk + kb*8);
    *(uint4*)&dst[row*64 + ((kb ^ (row & 7)) << 3)] = v;
  }
}

// ---------------------------------------------------------------------------
// MFMA GEMM, single bf16: C = epi(A @ B). A,B pre-converted bf16 [row][k].
// EPI: 1=+bias->f32  4=*wcol->bf16  5=Cf32+= ->bf16  6=+bias->bf16
// ---------------------------------------------------------------------------
template<int BM,int BN,bool QKV,int EPI>
__global__ __launch_bounds__(256)
void mgemm(int K,
  const short* __restrict__ AB, int lda, long sAb, long sAh,
  const short* __restrict__ BB, long sBb, long sBh,
  float* __restrict__ C, int ldc, long sCb, long sCh,
  const float* __restrict__ bias, const float* __restrict__ bias1, const float* __restrict__ bias2,
  const float* __restrict__ wcolp, short* __restrict__ CB, int Hdiv)
{
  __shared__ short As[BM*64], Bs[BN*64];
  constexpr int WMT = BM/2, WNT = BN/2;
  constexpr int FM = WMT/16, FN = WNT/16;

  const int z = blockIdx.z;
  const int zb = z / Hdiv, zh = z % Hdiv;
  const short* Ab = AB;
  const short* Bb = BB;
  float* Cb = C;
  short* Cbb = CB;
  if constexpr (QKV){
    Ab += (long)zb*4194304;
    if constexpr (EPI >= 4) Cbb += (long)zb*4194304;
  } else {
    Ab += (long)zb*sAb + (long)zh*sAh;
    Bb += (long)zb*sBb + (long)zh*sBh;
    if (C) Cb += (long)zb*sCb + (long)zh*sCh;
    if constexpr (EPI >= 4) Cbb += (long)zb*sCb + (long)zh*sCh;
  }

  const int t = threadIdx.x;
  const int m0 = blockIdx.y*BM, n0 = blockIdx.x*BN;
  const int wave = t >> 6, lane = t & 63;
  const int wr = wave >> 1, wc = wave & 1;
  const int lr = lane & 15, lk = lane >> 4;

  f32x4 acc[FM][FN];
#pragma unroll
  for (int mi = 0; mi < FM; mi++)
#pragma unroll
    for (int nj = 0; nj < FN; nj++) acc[mi][nj] = (f32x4){0.f, 0.f, 0.f, 0.f};

  for (int k0 = 0; k0 < K; k0 += 64){
    stage_sb<BM>(Ab + (long)m0*lda + k0, lda, As, t);
    stage_sb<BN>(Bb + (long)n0*K + k0, K, Bs, t);
    __syncthreads();
#pragma unroll
    for (int kk = 0; kk < 2; kk++){
      bf16x8 ah[FM], bh[FN];
#pragma unroll
      for (int mi = 0; mi < FM; mi++){
        int row = wr*WMT + mi*16 + lr;
        ah[mi] = *(const bf16x8*)&As[row*64 + (((kk*4 + lk) ^ (row & 7)) << 3)];
      }
#pragma unroll
      for (int nj = 0; nj < FN; nj++){
        int col = wc*WNT + nj*16 + lr;
        bh[nj] = *(const bf16x8*)&Bs[col*64 + (((kk*4 + lk) ^ (col & 7)) << 3)];
      }
#pragma unroll
      for (int mi = 0; mi < FM; mi++)
#pragma unroll
        for (int nj = 0; nj < FN; nj++)
          acc[mi][nj] = __builtin_amdgcn_mfma_f32_16x16x32_bf16(ah[mi], bh[nj], acc[mi][nj], 0, 0, 0);
    }
    __syncthreads();
  }

  const float* wz = nullptr;
  if constexpr (EPI == 4) wz = wcolp + (long)z*512;
  const float* bp = bias;
  if constexpr (QKV) bp = (zb == 0) ? bias : ((zb == 1) ? bias1 : bias2);

#pragma unroll
  for (int mi = 0; mi < FM; mi++){
#pragma unroll
    for (int r = 0; r < 4; r++){
      int grow = m0 + wr*WMT + mi*16 + lk*4 + r;
#pragma unroll
      for (int nj = 0; nj < FN; nj++){
        int gcol = n0 + wc*WNT + nj*16 + lr;
        float v = acc[mi][nj][r];
        if constexpr (EPI == 1 || EPI == 6) v += bp[gcol];
        if constexpr (EPI == 5) v += Cb[(long)grow*ldc + gcol];
        if constexpr (EPI == 4) v *= wz[gcol];
        if constexpr (EPI >= 4) Cbb[(long)grow*ldc + gcol] = (short)f2bf(v);
        else                    Cb[(long)grow*ldc + gcol] = v;
      }
    }
  }
}

// ---------------------------------------------------------------------------
// Weight transpose + bf16 convert (Wq,Wk,Wv,Wo -> [n][k])
// ---------------------------------------------------------------------------
__global__ __launch_bounds__(256)
void wconv_t(const float* __restrict__ W0, const float* __restrict__ W1,
             const float* __restrict__ W2, const float* __restrict__ W3,
             short* B0, short* B1, short* B2, short* B3)
{
  const float* W; short* Bp;
  switch (blockIdx.z){
    case 0:  W = W0; Bp = B0; break;
    case 1:  W = W1; Bp = B1; break;
    case 2:  W = W2; Bp = B2; break;
    default: W = W3; Bp = B3; break;
  }
  __shared__ float s[64][65];
  const int r0 = blockIdx.y*64, c0 = blockIdx.x*64;
  const int t = threadIdx.x;
#pragma unroll
  for (int i = 0; i < 4; i++){
    int idx = t + i*256;
    int r = idx >> 4, c4 = (idx & 15)*4;
    float4 v = *(const float4*)(W + (long)(r0 + r)*512 + c0 + c4);
    s[r][c4+0] = v.x; s[r][c4+1] = v.y; s[r][c4+2] = v.z; s[r][c4+3] = v.w;
  }
  __syncthreads();
#pragma unroll
  for (int i = 0; i < 2; i++){
    int p = t + i*256;
    int n = p >> 3, kb = p & 7;
    float f[8];
#pragma unroll
    for (int j = 0; j < 8; j++) f[j] = s[kb*8 + j][n];
    *(uint4*)&Bp[(long)(c0 + n)*512 + r0 + kb*8] = cvt8s(f);
  }
}

// ---------------------------------------------------------------------------
// U -> bf16 in BOTH layouts: UB row-major [l][i], UtB [i][l]
// ---------------------------------------------------------------------------
__global__ __launch_bounds__(256)
void uconv(const float* __restrict__ U, short* __restrict__ UB, short* __restrict__ UtB)
{
  __shared__ float s[64][65];
  const int r0 = blockIdx.y*64, c0 = blockIdx.x*64;
  const int t = threadIdx.x;
#pragma unroll
  for (int i = 0; i < 4; i++){
    int idx = t + i*256;
    int r = idx >> 4, c4 = (idx & 15)*4;
    float4 v = *(const float4*)(U + (long)(r0 + r)*512 + c0 + c4);
    s[r][c4+0] = v.x; s[r][c4+1] = v.y; s[r][c4+2] = v.z; s[r][c4+3] = v.w;
  }
  __syncthreads();
#pragma unroll
  for (int i = 0; i < 2; i++){
    int p = t + i*256;
    int rr = p >> 3, kb = p & 7;
    float f[8];
#pragma unroll
    for (int j = 0; j < 8; j++) f[j] = s[rr][kb*8 + j];
    *(uint4*)&UB[(long)(r0 + rr)*512 + c0 + kb*8] = cvt8s(f);
  }
#pragma unroll
  for (int i = 0; i < 2; i++){
    int p = t + i*256;
    int n = p >> 3, kb = p & 7;
    float f[8];
#pragma unroll
    for (int j = 0; j < 8; j++) f[j] = s[kb*8 + j][n];
    *(uint4*)&UtB[(long)(c0 + n)*512 + r0 + kb*8] = cvt8s(f);
  }
}

// ---------------------------------------------------------------------------
// Activation pre-convert: q,k,v -> bf16 row-major
// ---------------------------------------------------------------------------
__global__ __launch_bounds__(256)
void acvt(const float* __restrict__ q, const float* __restrict__ k,
          const float* __restrict__ v, short* __restrict__ base)
{
  long g = (long)blockIdx.x*256 + threadIdx.x;
  if (g >= 1572864) return;
  long idx = g & 524287; int sel = (int)(g >> 19);
  const float* src = sel == 0 ? q : (sel == 1 ? k : v);
  short* Bp = base + (long)sel*4194304;
  float f[8];
  *(float4*)&f[0] = *(const float4*)(src + idx*8);
  *(float4*)&f[4] = *(const float4*)(src + idx*8 + 4);
  *(uint4*)&Bp[idx*8] = cvt8s(f);
}

// ---------------------------------------------------------------------------
// Fused skinny projection + phases; blockIdx.y selects (q|k).
// ---------------------------------------------------------------------------
__global__ __launch_bounds__(256)
void skinny_k(const float* __restrict__ Xq, const float* __restrict__ Xk,
              const float* __restrict__ Wqo, const float* __restrict__ bqo,
              const float* __restrict__ Wqt, const float* __restrict__ bqt,
              const float* __restrict__ Wko, const float* __restrict__ bko,
              const float* __restrict__ Wkt, const float* __restrict__ bkt,
              float* __restrict__ q_om, float* __restrict__ q_th, float* __restrict__ Cq,
              float* __restrict__ k_om, float* __restrict__ k_th, float* __restrict__ Ck)
{
    const int sel = blockIdx.y;
    const float* X   = sel ? Xk  : Xq;
    const float* Wom = sel ? Wko : Wqo;  const float* bom = sel ? bko : bqo;
    const float* Wth = sel ? Wkt : Wqt;  const float* bth = sel ? bkt : bqt;
    float* om_out = sel ? k_om : q_om;
    float* th_out = sel ? k_th : q_th;
    float* Cph    = sel ? Ck   : Cq;

    const int t = threadIdx.x;
    const int tx = t & 31, ty = t >> 5;
    const long row = (long)blockIdx.x * 8 + ty;
    const int col = tx & 15;
    const bool isTh = tx >= 16;
    const float* __restrict__ Wm = isTh ? Wth : Wom;
    const float* __restrict__ xr = X + row * 512;
    float acc0 = 0.f, acc1 = 0.f, acc2 = 0.f, acc3 = 0.f;
    for (int k = 0; k < 512; k += 4) {
        acc0 += xr[k + 0] * Wm[(k + 0) * 16 + col];
        acc1 += xr[k + 1] * Wm[(k + 1) * 16 + col];
        acc2 += xr[k + 2] * Wm[(k + 2) * 16 + col];
        acc3 += xr[k + 3] * Wm[(k + 3) * 16 + col];
    }
    float acc = (acc0 + acc1) + (acc2 + acc3);
    __shared__ float som[8][16], sth[8][16];
    float res;
    if (isTh) {
        res = tanhf(acc + bth[col]) * PI_F;
        th_out[row * 16 + col] = res;
        sth[ty][col] = res;
    } else {
        res = fmaxf(acc + bom[col], 0.f);
        om_out[row * 16 + col] = res;
        som[ty][col] = res;
    }
    __syncthreads();
    if (t < 64){
        const int r2 = t >> 3, h = t & 7;
        const long grow = (long)blockIdx.x * 8 + r2;
        const float tt = (float)(grow & 511);
        const float o0 = som[r2][h*2], o1 = som[r2][h*2+1];
        const float t0 = sth[r2][h*2], t1 = sth[r2][h*2+1];
        float c0, s0, c1, s1;
        sincosf(o0 * tt + t0, &s0, &c0);
        sincosf(o1 * tt + t1, &s1, &c1);
        float4 rr = { c0, s0, c1, s1 };
        *(float4*)&Cph[grow * 32 + h * 4] = rr;
    }
}

// ---------------------------------------------------------------------------
// FUSED moving average over bf16 input; z>>4 selects source.
// src 0/1: residual -> row-major bf16. src 2: res^T -> VTB, trend^T -> TTB.
// ---------------------------------------------------------------------------
__global__ __launch_bounds__(256)
void movavg_all(const short* __restrict__ qpB, const short* __restrict__ kpB,
                const short* __restrict__ vpB,
                short* __restrict__ qRB, short* __restrict__ kRB,
                short* __restrict__ VTB, short* __restrict__ TTB)
{
    const int zz = blockIdx.z;
    const int src = zz >> 4, b = zz & 15;
    const int l0 = blockIdx.y * 64, c0 = blockIdx.x * 64;
    const short* XB = src == 0 ? qpB : (src == 1 ? kpB : vpB);
    short* RB = src == 0 ? qRB : kRB;
    __shared__ float sm[88][64];
    const long base = (long)b * 512 * 512 + c0;
    const int t = threadIdx.x;
    for (int i = t; i < 88 * 64; i += 256) {
        const int r = i >> 6, c = i & 63;
        int gl = l0 + r - 12;
        gl = min(max(gl, 0), 511);
        sm[r][c] = bf2f((ushort)XB[base + (long)gl * 512 + c]);
    }
    __syncthreads();
    const int tx = t & 63, ty = t >> 6;
    const int rbase = ty * 16;
    float s = 0.f;
    #pragma unroll
    for (int d = 0; d < 25; d++) s += sm[rbase + d][tx];
    const float inv = 1.f / 25.f;
    short hb[16], tb[16];
    #pragma unroll
    for (int r = 0; r < 16; r++) {
        const long l = l0 + rbase + r;
        const float ma = s * inv;
        const float x = sm[rbase + r + 12][tx];
        const float res = x - ma;
        if (src < 2) {
            RB[((long)b * 512 + l) * 512 + c0 + tx] = (short)f2bf(res);
        } else {
            hb[r] = (short)f2bf(res);
            tb[r] = (short)f2bf(ma);
        }
        if (r < 15) s += sm[rbase + r + 25][tx] - sm[rbase + r][tx];
    }
    if (src == 2) {
        const long vo = ((long)b * 512 + c0 + tx) * 512 + l0 + rbase;
        *(uint4*)&VTB[vo]     = ((uint4*)hb)[0];
        *(uint4*)&VTB[vo + 8] = ((uint4*)hb)[1];
        *(uint4*)&TTB[vo]     = ((uint4*)tb)[0];
        *(uint4*)&TTB[vo + 8] = ((uint4*)tb)[1];
    }
}

// ---------------------------------------------------------------------------
// Flash attention v6: v5 packed scores + coalesced attn store via PPs re-read
// (4 float4 stores/thread/stage instead of 16 scalars).
// ---------------------------------------------------------------------------
__global__ __launch_bounds__(256)
void flash_k(const short* __restrict__ qB, const short* __restrict__ kB,
             const short* __restrict__ vtB,
             const float* __restrict__ Cq, const float* __restrict__ Ck,
             float* __restrict__ attn, float* __restrict__ attn_out)
{
  const int bid = blockIdx.y*8 + blockIdx.x;
  const int swz = (bid & 7)*128 + (bid >> 3);
  const int z = swz >> 3; const int b = z >> 3, h = z & 7;
  const int l0 = (swz & 7) * 64;
  const int t = threadIdx.x, wave = t >> 6, lane = t & 63;
  const int lr = lane & 15, lk = lane >> 4;

  __shared__ short SH[8192];
  __shared__ float CkS[2048];
  short* Qs = SH;
  short* Ks = SH;
  short* PPs = SH;
  short* Vs = SH + 4096;

  const int sr0 = t >> 3,          skb0 = t & 7;
  const int sr1 = (t >> 3) + 32,   skb1 = t & 7;
  const int sidx0 = sr0*64 + ((skb0 ^ (sr0 & 7)) << 3);
  const int sidx1 = sr1*64 + ((skb1 ^ (sr1 & 7)) << 3);

  stage_sync<64>(qB + ((long)(b*512 + l0))*512 + h*64, 512, Qs, t);
#pragma unroll
  for (int i = 0; i < 2; i++){
    int s = t + i*256;
    ((float4*)CkS)[s] = *(const float4*)(Ck + (((long)b*512 + s)*8 + h)*4);
  }
  __syncthreads();
  bf16x8 aq[2];
#pragma unroll
  for (int kk = 0; kk < 2; kk++){
    int row = wave*16 + lr;
    aq[kk] = *(const bf16x8*)&Qs[row*64 + (((kk*4 + lk) ^ (row & 7)) << 3)];
  }
  float4 cqv[4];
#pragma unroll
  for (int r = 0; r < 4; r++){
    int row = l0 + wave*16 + lk*4 + r;
    cqv[r] = *(const float4*)(Cq + (((long)b*512 + row)*8 + h)*4);
  }

  const long kbase0 = ((long)(b*512 + sr0))*512 + h*64 + skb0*8;
  const long kbase1 = ((long)(b*512 + sr1))*512 + h*64 + skb1*8;
  uint4 pA0, pA1, pB0, pB1;
  pA0 = *(const uint4*)(kB + kbase0);
  pA1 = *(const uint4*)(kB + kbase1);
  __syncthreads();

  // scores: 8 stages of 64 K-rows; per-stage finalize+modulate+pack to bf16.
  uint pk[64];
#pragma unroll
  for (int st = 0; st < 8; st++){
    if (st & 1){
      *(uint4*)&Ks[sidx0] = pB0; *(uint4*)&Ks[sidx1] = pB1;
      if (st < 7){
        pA0 = *(const uint4*)(kB + kbase0 + (long)(st+1)*64*512);
        pA1 = *(const uint4*)(kB + kbase1 + (long)(st+1)*64*512);
      }
    } else {
      *(uint4*)&Ks[sidx0] = pA0; *(uint4*)&Ks[sidx1] = pA1;
      if (st < 7){
        pB0 = *(const uint4*)(kB + kbase0 + (long)(st+1)*64*512);
        pB1 = *(const uint4*)(kB + kbase1 + (long)(st+1)*64*512);
      }
    }
    __syncthreads();
    f32x4 tmp[4];
#pragma unroll
    for (int nj = 0; nj < 4; nj++) tmp[nj] = (f32x4){0.f,0.f,0.f,0.f};
#pragma unroll
    for (int nj = 0; nj < 4; nj++){
      int srow = nj*16 + lr;
#pragma unroll
      for (int kk = 0; kk < 2; kk++){
        bf16x8 bh = *(const bf16x8*)&Ks[srow*64 + (((kk*4 + lk) ^ (srow & 7)) << 3)];
        tmp[nj] = __builtin_amdgcn_mfma_f32_16x16x32_bf16(aq[kk], bh, tmp[nj], 0,0,0);
      }
    }
#pragma unroll
    for (int nj = 0; nj < 4; nj++){
      int col = st*64 + nj*16 + lr;
      float4 ckv = ((float4*)CkS)[col];
#pragma unroll
      for (int r = 0; r < 4; r++){
        float mod = 0.125f*(cqv[r].x*ckv.x + cqv[r].y*ckv.y + cqv[r].z*ckv.z + cqv[r].w*ckv.w);
        tmp[nj][r] *= mod;
      }
    }
#pragma unroll
    for (int nj2 = 0; nj2 < 2; nj2++)
#pragma unroll
      for (int r = 0; r < 4; r++)
        pk[st*8 + nj2*4 + r] = (uint)f2bf(tmp[nj2*2][r]) | ((uint)f2bf(tmp[nj2*2+1][r]) << 16);
    if (st < 7) __syncthreads();
  }

  const long vbase0 = ((long)(z*64 + sr0))*512 + skb0*8;
  const long vbase1 = ((long)(z*64 + sr1))*512 + skb1*8;
  pA0 = *(const uint4*)(vtB + vbase0);
  pA1 = *(const uint4*)(vtB + vbase1);

  // softmax over packed scores
  float mx[4] = {-INFINITY, -INFINITY, -INFINITY, -INFINITY};
#pragma unroll
  for (int g = 0; g < 16; g++)
#pragma unroll
    for (int r = 0; r < 4; r++){
      uint u = pk[g*4 + r];
      mx[r] = fmaxf(mx[r], fmaxf(bf2f((ushort)(u & 0xffffu)), bf2f((ushort)(u >> 16))));
    }
#pragma unroll
  for (int msk = 1; msk < 16; msk <<= 1)
#pragma unroll
    for (int r = 0; r < 4; r++) mx[r] = fmaxf(mx[r], __shfl_xor(mx[r], msk));
  float sme[4] = {0.f, 0.f, 0.f, 0.f};
#pragma unroll
  for (int g = 0; g < 16; g++)
#pragma unroll
    for (int r = 0; r < 4; r++){
      uint u = pk[g*4 + r];
      float e0 = __expf(bf2f((ushort)(u & 0xffffu)) - mx[r]);
      float e1 = __expf(bf2f((ushort)(u >> 16)) - mx[r]);
      sme[r] += e0 + e1;
      pk[g*4 + r] = (uint)f2bf(e0) | ((uint)f2bf(e1) << 16);
    }
#pragma unroll
  for (int msk = 1; msk < 16; msk <<= 1)
#pragma unroll
    for (int r = 0; r < 4; r++) sme[r] += __shfl_xor(sme[r], msk);
  float inv[4];
#pragma unroll
  for (int r = 0; r < 4; r++) inv[r] = 1.f / sme[r];

  // PV: 8 stages of 64 s-cols; P (scaled) -> PPs; attn written from PPs
  // with coalesced float4 stores.
  f32x4 oacc[4];
#pragma unroll
  for (int nj = 0; nj < 4; nj++) oacc[nj] = (f32x4){0.f,0.f,0.f,0.f};
  const long abase = ((long)z*512 + l0)*512;
#pragma unroll
  for (int st = 0; st < 8; st++){
    __syncthreads();
#pragma unroll
    for (int a2 = 0; a2 < 4; a2++){
      int c = a2*16 + lr;
#pragma unroll
      for (int r = 0; r < 4; r++){
        uint u = pk[st*8 + (a2 >> 1)*4 + r];
        float e = bf2f((ushort)((a2 & 1) ? (u >> 16) : (u & 0xffffu)));
        float p = e * inv[r];
        int row = wave*16 + lk*4 + r;
        PPs[row*64 + (((c >> 3) ^ (row & 7)) << 3) + (c & 7)] = (short)f2bf(p);
      }
    }
    if (st & 1){
      *(uint4*)&Vs[sidx0] = pB0; *(uint4*)&Vs[sidx1] = pB1;
      if (st < 7){
        pA0 = *(const uint4*)(vtB + vbase0 + (st+1)*64);
        pA1 = *(const uint4*)(vtB + vbase1 + (st+1)*64);
      }
    } else {
      *(uint4*)&Vs[sidx0] = pA0; *(uint4*)&Vs[sidx1] = pA1;
      if (st < 7){
        pB0 = *(const uint4*)(vtB + vbase0 + (st+1)*64);
        pB1 = *(const uint4*)(vtB + vbase1 + (st+1)*64);
      }
    }
    __syncthreads();
    // coalesced attn store: each thread reads one swizzled bf16x8 row-segment
    // of PPs and writes two float4s (4 float4/thread/stage total).
#pragma unroll
    for (int u2 = 0; u2 < 2; u2++){
      int uu = t + u2*256;
      int row = uu >> 3, j = uu & 7;
      bf16x8 pv8 = *(const bf16x8*)&PPs[row*64 + ((j ^ (row & 7)) << 3)];
      float4 f0, f1;
      f0.x = bf2f((ushort)pv8[0]); f0.y = bf2f((ushort)pv8[1]);
      f0.z = bf2f((ushort)pv8[2]); f0.w = bf2f((ushort)pv8[3]);
      f1.x = bf2f((ushort)pv8[4]); f1.y = bf2f((ushort)pv8[5]);
      f1.z = bf2f((ushort)pv8[6]); f1.w = bf2f((ushort)pv8[7]);
      float* ap = attn + abase + (long)row*512 + st*64 + j*8;
      *(float4*)ap = f0; *(float4*)(ap + 4) = f1;
    }
#pragma unroll
    for (int kk = 0; kk < 2; kk++){
      int prow = wave*16 + lr;
      int phys = (kk*4 + lk) ^ (prow & 7);
      bf16x8 ah = *(const bf16x8*)&PPs[prow*64 + phys*8];
#pragma unroll
      for (int nj = 0; nj < 4; nj++){
        int vrow = nj*16 + lr;
        bf16x8 bh = *(const bf16x8*)&Vs[vrow*64 + (((kk*4 + lk) ^ (vrow & 7)) << 3)];
        oacc[nj] = __builtin_amdgcn_mfma_f32_16x16x32_bf16(ah, bh, oacc[nj], 0,0,0);
      }
    }
  }
#pragma unroll
  for (int nj = 0; nj < 4; nj++)
#pragma unroll
    for (int r = 0; r < 4; r++){
      int grow = l0 + wave*16 + lk*4 + r;
      attn_out[((long)b*512 + grow)*512 + h*64 + nj*16 + lr] = oacc[nj][r];
    }
}

// ---------------------------------------------------------------------------
// Lambda conv + w, reading trend^T bf16 (TTB[(b*512+c)][l]).
// ---------------------------------------------------------------------------
__global__ __launch_bounds__(512)
void lamw_k(const short* __restrict__ TTB, const float* __restrict__ Wlam,
            const float* __restrict__ blam, const float* __restrict__ Sv,
            float* __restrict__ Wout)
{
    const int z = blockIdx.x;
    const int b = z >> 3, h = z & 7;
    __shared__ float sv[512][17];
    __shared__ float sw[448];
    const int t = threadIdx.x;
    if (t < 448) sw[t] = Wlam[t];
    const short* __restrict__ Tb = TTB + ((long)b * 512 + h * 64) * 512;
    float lam = 0.f;
    for (int ec = 0; ec < 4; ec++) {
        __syncthreads();
        #pragma unroll
        for (int j = 0; j < 16; j++)
            sv[t][j] = bf2f((ushort)Tb[(long)(ec * 16 + j) * 512 + t]);
        __syncthreads();
        #pragma unroll
        for (int dk = 0; dk < 7; dk++) {
            int r = t + dk - 3;
            r = min(max(r, 0), 511);
            #pragma unroll
            for (int j = 0; j < 16; j++)
                lam += sv[r][j] * sw[(ec * 16 + j) * 7 + dk];
        }
    }
    lam += blam[0];
    const float el = lam > 0.f ? lam : expm1f(lam);
    const float wv = 1.f / (1.f + (1.f + el) * Sv[t]);
    Wout[(long)z * 512 + t] = wv;
}

// ---------------------------------------------------------------------------
__global__ __launch_bounds__(256)
void pen1_k(const float* __restrict__ qom, const float* __restrict__ kom,
            const float* __restrict__ qth, const float* __restrict__ kth,
            float* __restrict__ partials)
{
    const long tid = (long)blockIdx.x * 256 + threadIdx.x;
    float om = 0.f, th = 0.f;
    for (long i = tid; i < 262144; i += 65536) {
        const float* om_arr = (i < 131072) ? qom : kom;
        const float* th_arr = (i < 131072) ? qth : kth;
        const long j = i & 131071;
        const float x = th_arr[j];
        th += x * x;
        const int l = (int)((j >> 4) & 511);
        if (l < 511) {
            const float d = om_arr[j + 16] - om_arr[j];
            om += d * d;
        }
    }
    __shared__ float som[256], sth[256];
    som[threadIdx.x] = om; sth[threadIdx.x] = th;
    __syncthreads();
    for (int o = 128; o; o >>= 1) {
        if (threadIdx.x < o) {
            som[threadIdx.x] += som[threadIdx.x + o];
            sth[threadIdx.x] += sth[threadIdx.x + o];
        }
        __syncthreads();
    }
    if (threadIdx.x == 0) {
        partials[blockIdx.x] = som[0];
        partials[256 + blockIdx.x] = sth[0];
    }
}

__global__ __launch_bounds__(256)
void pen2_k(const float* __restrict__ partials, float* __restrict__ om_out,
            float* __restrict__ th_out)
{
    __shared__ float som[256], sth[256];
    const int t = threadIdx.x;
    som[t] = partials[t]; sth[t] = partials[256 + t];
    __syncthreads();
    for (int o = 128; o; o >>= 1) {
        if (t < o) { som[t] += som[t + o]; sth[t] += sth[t + o]; }
        __syncthreads();
    }
    if (t == 0) { *om_out = som[0]; *th_out = sth[0]; }
}

// ---------------------------------------------------------------------------
extern "C" void kernel_launch(void* const* d_in, const int* in_sizes, int n_in,
                              void* d_out_v, int out_size, void* d_ws, size_t ws_size,
                              hipStream_t stream)
{
    const float* queries = (const float*)d_in[0];
    const float* keys    = (const float*)d_in[1];
    const float* values  = (const float*)d_in[2];
    const float* Wq  = (const float*)d_in[3];  const float* bq  = (const float*)d_in[4];
    const float* Wk  = (const float*)d_in[5];  const float* bk  = (const float*)d_in[6];
    const float* Wv  = (const float*)d_in[7];  const float* bv  = (const float*)d_in[8];
    const float* Wqo = (const float*)d_in[9];  const float* bqo = (const float*)d_in[10];
    const float* Wko = (const float*)d_in[11]; const float* bko = (const float*)d_in[12];
    const float* Wqt = (const float*)d_in[13]; const float* bqt = (const float*)d_in[14];
    const float* Wkt = (const float*)d_in[15]; const float* bkt = (const float*)d_in[16];
    const float* Wo  = (const float*)d_in[17]; const float* bo  = (const float*)d_in[18];
    const float* Wlam= (const float*)d_in[19]; const float* blam= (const float*)d_in[20];
    const float* U   = (const float*)d_in[21]; const float* Sv  = (const float*)d_in[22];

    float* out = (float*)d_out_v;
    float* W   = (float*)d_ws;

    short* qpB = (short*)W;
    short* kpB = (short*)(W + 4194304);
    short* vpB = (short*)(W + 8388608);
    float* attn_out = W + 4194304;
    short* TTB = (short*)(W + 12582912);
    short* R1  = (short*)(W + 16777216);
    short* qinB = R1;
    short* kinB = R1 + 4194304;
    short* vinB = R1 + 8388608;
    short* qresB = qinB;  short* kresB = kinB;  short* vtB = vinB;
    short* aoB = kresB;
    short* T1tB = (short*)W;
    short* UB  = (short*)(W + 8388608);
    short* UtB = UB + 262144;
    float* q_om = W + 29360128;
    float* k_om = q_om + 131072;
    float* q_th = k_om + 131072;
    float* k_th = q_th + 131072;
    float* Cq   = k_th + 131072;
    float* Ck   = Cq + 262144;
    float* wbuf = Ck + 262144;
    float* partials = wbuf + 65536;
    short* wsp = (short*)(W + 30475264);
    short* WqB = wsp;
    short* WkB = wsp + 262144;
    short* WvB = wsp + 524288;
    short* WoB = wsp + 786432;

    float* attn = out + ATTN_OFF;
    dim3 blk(256);

    // 0. pre-converts
    wconv_t<<<dim3(8,8,4), blk, 0, stream>>>(Wq, Wk, Wv, Wo, WqB, WkB, WvB, WoB);
    acvt<<<dim3(6144), blk, 0, stream>>>(queries, keys, values, R1);

    // 1. fused QKV projection -> bf16 (EPI 6)
    mgemm<128,128,true,6><<<dim3(4,64,3), blk, 0, stream>>>(
        512, qinB, 512, 0, 0, WqB, 0, 0,
        nullptr, 512, 0, 0,
        bq, bk, bv, nullptr, qpB, 1);

    // 2. fused omega/theta projections + phase tables
    skinny_k<<<dim3(1024,2), blk, 0, stream>>>(queries, keys,
        Wqo, bqo, Wqt, bqt, Wko, bko, Wkt, bkt,
        q_om, q_th, Cq, k_om, k_th, Ck);

    // 3. fused series decomposition
    movavg_all<<<dim3(8,8,48), blk, 0, stream>>>(qpB, kpB, vpB,
        qresB, kresB, vtB, TTB);

    // 3.5 U -> bf16 (both layouts), into now-dead vp region
    uconv<<<dim3(8,8), blk, 0, stream>>>(U, UB, UtB);

    // 4. fused scores+softmax+attn-write+PV (v6: coalesced attn store)
    flash_k<<<dim3(8,128), blk, 0, stream>>>(qresB, kresB, vtB, Cq, Ck, attn, attn_out);

    // 5. lambda conv -> w (reads trend^T bf16)
    lamw_k<<<dim3(128), dim3(512), 0, stream>>>(TTB, Wlam, blam, Sv, wbuf);

    // 6. T1t[e][i] = (sum_l trend[l][e] U[l][i]) * w[i] -> bf16 (EPI 4)
    mgemm<64,128,false,4><<<dim3(4,1,128), blk, 0, stream>>>(
        512, TTB, 512, 262144, 32768, UtB, 0, 0,
        nullptr, 512, 262144, 32768,
        nullptr, nullptr, nullptr, wbuf, T1tB, 8);

    // 7. aoB(bf16) = attn_out(f32) + U @ T1  (EPI 5)
    mgemm<128,64,false,5><<<dim3(1,4,128), blk, 0, stream>>>(
        512, UB, 512, 0, 0, T1tB, 262144, 32768,
        attn_out, 512, 262144, 64,
        nullptr, nullptr, nullptr, nullptr, aoB, 8);

    // 8. out projection (EPI 1)
    mgemm<64,128,false,1><<<dim3(4,128,1), blk, 0, stream>>>(
        512, aoB, 512, 0, 0, WoB, 0, 0,
        out, 512, 0, 0,
        bo, nullptr, nullptr, nullptr, nullptr, 1);

    // 9. penalties
    pen1_k<<<dim3(256), blk, 0, stream>>>(q_om, k_om, q_th, k_th, partials);
    pen2_k<<<dim3(1), blk, 0, stream>>>(partials, out + OM_OFF, out + TH_OFF);
}

// Round 20
// 226.274 us; speedup vs baseline: 1.0027x; 1.0027x over previous
//
#include <hip/hip_runtime.h>
#include <math.h>

// B=16, L=512, D_MODEL=512, H=8, M=2, E=64, KMA=25, KLAM=7
// Outputs (f32, concat): out (16,512,512) | attn (16,8,512,512) | om_pen | th_pen
// Single-bf16 arithmetic everywhere.

#define PI_F 3.14159265358979323846f

typedef __attribute__((ext_vector_type(8))) short bf16x8;
typedef __attribute__((ext_vector_type(4))) float f32x4;

static constexpr long ATTN_OFF = 4194304;
static constexpr long OM_OFF   = 37748736;
static constexpr long TH_OFF   = 37748737;

// ---------------------------------------------------------------------------
__device__ __forceinline__ ushort f2bf(float f){
  uint u = __float_as_uint(f);
  u += 0x7fffu + ((u >> 16) & 1u);
  return (ushort)(u >> 16);
}
__device__ __forceinline__ float bf2f(ushort h){
  return __uint_as_float((uint)h << 16);
}
__device__ __forceinline__ uint4 cvt8s(const float* f){
  ushort h[8];
#pragma unroll
  for (int j = 0; j < 8; j++) h[j] = f2bf(f[j]);
  uint4 H;
  H.x = (uint)h[0] | ((uint)h[1] << 16); H.y = (uint)h[2] | ((uint)h[3] << 16);
  H.z = (uint)h[4] | ((uint)h[5] << 16); H.w = (uint)h[6] | ((uint)h[7] << 16);
  return H;
}

// ---------------------------------------------------------------------------
// Single-stream async LDS staging: dest lane-linear (p*16B), swizzle moved to
// global source via involution kb = (p&7)^(row&7)  (rule #21).
// ---------------------------------------------------------------------------
template<int ROWS>
__device__ __forceinline__ void stage_sb(const short* __restrict__ G, int ldk,
                                         short* dst, int t){
#pragma unroll
  for (int i = 0; i < ROWS*8/256; i++){
    int p = t + i*256;
    int row = p >> 3;
    int kb = (p & 7) ^ (row & 7);
    __builtin_amdgcn_global_load_lds(
        (const __attribute__((address_space(1))) uint*)(G + (long)row*ldk + kb*8),
        (__attribute__((address_space(3))) uint*)(dst + (long)p*8), 16, 0, 0);
  }
}

// f32 source with in-staging bf16 convert (register round-trip), same layout.
template<int ROWS>
__device__ __forceinline__ void stage_f32(const float* __restrict__ G, int ldk,
                                          short* dst, int t){
#pragma unroll
  for (int i = 0; i < ROWS*8/256; i++){
    int p = t + i*256;
    int row = p >> 3;
    int kb = (p & 7) ^ (row & 7);
    const float* g = G + (long)row*ldk + kb*8;
    float f[8];
    *(float4*)&f[0] = *(const float4*)g;
    *(float4*)&f[4] = *(const float4*)(g + 4);
    *(uint4*)&dst[(long)p*8] = cvt8s(f);
  }
}

// sync single-stream stage (register round-trip) — flash Q
template<int ROWS>
__device__ __forceinline__ void stage_sync(const short* __restrict__ G, int ldk,
                                           short* dst, int t){
#pragma unroll
  for (int i = 0; i < ROWS*8/256; i++){
    int p = t + i*256;
    int row = p >> 3, kb = p & 7;
    uint4 v = *(const uint4*)(G + (long)row*ldk + kb*8);
    *(uint4*)&dst[row*64 + ((kb ^ (row & 7)) << 3)] = v;
  }
}

// ---------------------------------------------------------------------------
// MFMA GEMM, single bf16: C = epi(A @ B). B pre-converted bf16 [row][k];
// A either bf16 (AF32=false) or f32 with in-staging convert (AF32=true).
// EPI: 1=+bias->f32  4=*wcol->bf16  5=Cf32+= ->bf16  6=+bias->bf16
// ---------------------------------------------------------------------------
template<int BM,int BN,bool QKV,bool AF32,int EPI>
__global__ __launch_bounds__(256)
void mgemm(int K,
  const short* __restrict__ AB, const float* __restrict__ AF0,
  const float* __restrict__ AF1, const float* __restrict__ AF2,
  int lda, long sAb, long sAh,
  const short* __restrict__ BB, long sBb, long sBh,
  float* __restrict__ C, int ldc, long sCb, long sCh,
  const float* __restrict__ bias, const float* __restrict__ bias1, const float* __restrict__ bias2,
  const float* __restrict__ wcolp, short* __restrict__ CB, int Hdiv)
{
  __shared__ short As[BM*64], Bs[BN*64];
  constexpr int WMT = BM/2, WNT = BN/2;
  constexpr int FM = WMT/16, FN = WNT/16;

  const int z = blockIdx.z;
  const int zb = z / Hdiv, zh = z % Hdiv;
  const short* Ab = AB;
  const float* Af = AF0;
  const short* Bb = BB;
  float* Cb = C;
  short* Cbb = CB;
  if constexpr (QKV){
    if constexpr (AF32) Af = (zb == 0) ? AF0 : ((zb == 1) ? AF1 : AF2);
    else Ab += (long)zb*4194304;
    if constexpr (EPI >= 4) Cbb += (long)zb*4194304;
  } else {
    Ab += (long)zb*sAb + (long)zh*sAh;
    Bb += (long)zb*sBb + (long)zh*sBh;
    if (C) Cb += (long)zb*sCb + (long)zh*sCh;
    if constexpr (EPI >= 4) Cbb += (long)zb*sCb + (long)zh*sCh;
  }

  const int t = threadIdx.x;
  const int m0 = blockIdx.y*BM, n0 = blockIdx.x*BN;
  const int wave = t >> 6, lane = t & 63;
  const int wr = wave >> 1, wc = wave & 1;
  const int lr = lane & 15, lk = lane >> 4;

  f32x4 acc[FM][FN];
#pragma unroll
  for (int mi = 0; mi < FM; mi++)
#pragma unroll
    for (int nj = 0; nj < FN; nj++) acc[mi][nj] = (f32x4){0.f, 0.f, 0.f, 0.f};

  for (int k0 = 0; k0 < K; k0 += 64){
    if constexpr (AF32) stage_f32<BM>(Af + (long)m0*lda + k0, lda, As, t);
    else                stage_sb<BM>(Ab + (long)m0*lda + k0, lda, As, t);
    stage_sb<BN>(Bb + (long)n0*K + k0, K, Bs, t);
    __syncthreads();
#pragma unroll
    for (int kk = 0; kk < 2; kk++){
      bf16x8 ah[FM], bh[FN];
#pragma unroll
      for (int mi = 0; mi < FM; mi++){
        int row = wr*WMT + mi*16 + lr;
        ah[mi] = *(const bf16x8*)&As[row*64 + (((kk*4 + lk) ^ (row & 7)) << 3)];
      }
#pragma unroll
      for (int nj = 0; nj < FN; nj++){
        int col = wc*WNT + nj*16 + lr;
        bh[nj] = *(const bf16x8*)&Bs[col*64 + (((kk*4 + lk) ^ (col & 7)) << 3)];
      }
#pragma unroll
      for (int mi = 0; mi < FM; mi++)
#pragma unroll
        for (int nj = 0; nj < FN; nj++)
          acc[mi][nj] = __builtin_amdgcn_mfma_f32_16x16x32_bf16(ah[mi], bh[nj], acc[mi][nj], 0, 0, 0);
    }
    __syncthreads();
  }

  const float* wz = nullptr;
  if constexpr (EPI == 4) wz = wcolp + (long)z*512;
  const float* bp = bias;
  if constexpr (QKV) bp = (zb == 0) ? bias : ((zb == 1) ? bias1 : bias2);

#pragma unroll
  for (int mi = 0; mi < FM; mi++){
#pragma unroll
    for (int r = 0; r < 4; r++){
      int grow = m0 + wr*WMT + mi*16 + lk*4 + r;
#pragma unroll
      for (int nj = 0; nj < FN; nj++){
        int gcol = n0 + wc*WNT + nj*16 + lr;
        float v = acc[mi][nj][r];
        if constexpr (EPI == 1 || EPI == 6) v += bp[gcol];
        if constexpr (EPI == 5) v += Cb[(long)grow*ldc + gcol];
        if constexpr (EPI == 4) v *= wz[gcol];
        if constexpr (EPI >= 4) Cbb[(long)grow*ldc + gcol] = (short)f2bf(v);
        else                    Cb[(long)grow*ldc + gcol] = v;
      }
    }
  }
}

// ---------------------------------------------------------------------------
// Weight transpose + bf16 convert (Wq,Wk,Wv,Wo -> [n][k])
// ---------------------------------------------------------------------------
__global__ __launch_bounds__(256)
void wconv_t(const float* __restrict__ W0, const float* __restrict__ W1,
             const float* __restrict__ W2, const float* __restrict__ W3,
             short* B0, short* B1, short* B2, short* B3)
{
  const float* W; short* Bp;
  switch (blockIdx.z){
    case 0:  W = W0; Bp = B0; break;
    case 1:  W = W1; Bp = B1; break;
    case 2:  W = W2; Bp = B2; break;
    default: W = W3; Bp = B3; break;
  }
  __shared__ float s[64][65];
  const int r0 = blockIdx.y*64, c0 = blockIdx.x*64;
  const int t = threadIdx.x;
#pragma unroll
  for (int i = 0; i < 4; i++){
    int idx = t + i*256;
    int r = idx >> 4, c4 = (idx & 15)*4;
    float4 v = *(const float4*)(W + (long)(r0 + r)*512 + c0 + c4);
    s[r][c4+0] = v.x; s[r][c4+1] = v.y; s[r][c4+2] = v.z; s[r][c4+3] = v.w;
  }
  __syncthreads();
#pragma unroll
  for (int i = 0; i < 2; i++){
    int p = t + i*256;
    int n = p >> 3, kb = p & 7;
    float f[8];
#pragma unroll
    for (int j = 0; j < 8; j++) f[j] = s[kb*8 + j][n];
    *(uint4*)&Bp[(long)(c0 + n)*512 + r0 + kb*8] = cvt8s(f);
  }
}

// ---------------------------------------------------------------------------
// U -> bf16 in BOTH layouts: UB row-major [l][i], UtB [i][l]
// ---------------------------------------------------------------------------
__global__ __launch_bounds__(256)
void uconv(const float* __restrict__ U, short* __restrict__ UB, short* __restrict__ UtB)
{
  __shared__ float s[64][65];
  const int r0 = blockIdx.y*64, c0 = blockIdx.x*64;
  const int t = threadIdx.x;
#pragma unroll
  for (int i = 0; i < 4; i++){
    int idx = t + i*256;
    int r = idx >> 4, c4 = (idx & 15)*4;
    float4 v = *(const float4*)(U + (long)(r0 + r)*512 + c0 + c4);
    s[r][c4+0] = v.x; s[r][c4+1] = v.y; s[r][c4+2] = v.z; s[r][c4+3] = v.w;
  }
  __syncthreads();
#pragma unroll
  for (int i = 0; i < 2; i++){
    int p = t + i*256;
    int rr = p >> 3, kb = p & 7;
    float f[8];
#pragma unroll
    for (int j = 0; j < 8; j++) f[j] = s[rr][kb*8 + j];
    *(uint4*)&UB[(long)(r0 + rr)*512 + c0 + kb*8] = cvt8s(f);
  }
#pragma unroll
  for (int i = 0; i < 2; i++){
    int p = t + i*256;
    int n = p >> 3, kb = p & 7;
    float f[8];
#pragma unroll
    for (int j = 0; j < 8; j++) f[j] = s[kb*8 + j][n];
    *(uint4*)&UtB[(long)(c0 + n)*512 + r0 + kb*8] = cvt8s(f);
  }
}

// ---------------------------------------------------------------------------
// Fused skinny projection + phases; blockIdx.y selects (q|k).
// ---------------------------------------------------------------------------
__global__ __launch_bounds__(256)
void skinny_k(const float* __restrict__ Xq, const float* __restrict__ Xk,
              const float* __restrict__ Wqo, const float* __restrict__ bqo,
              const float* __restrict__ Wqt, const float* __restrict__ bqt,
              const float* __restrict__ Wko, const float* __restrict__ bko,
              const float* __restrict__ Wkt, const float* __restrict__ bkt,
              float* __restrict__ q_om, float* __restrict__ q_th, float* __restrict__ Cq,
              float* __restrict__ k_om, float* __restrict__ k_th, float* __restrict__ Ck)
{
    const int sel = blockIdx.y;
    const float* X   = sel ? Xk  : Xq;
    const float* Wom = sel ? Wko : Wqo;  const float* bom = sel ? bko : bqo;
    const float* Wth = sel ? Wkt : Wqt;  const float* bth = sel ? bkt : bqt;
    float* om_out = sel ? k_om : q_om;
    float* th_out = sel ? k_th : q_th;
    float* Cph    = sel ? Ck   : Cq;

    const int t = threadIdx.x;
    const int tx = t & 31, ty = t >> 5;
    const long row = (long)blockIdx.x * 8 + ty;
    const int col = tx & 15;
    const bool isTh = tx >= 16;
    const float* __restrict__ Wm = isTh ? Wth : Wom;
    const float* __restrict__ xr = X + row * 512;
    float acc0 = 0.f, acc1 = 0.f, acc2 = 0.f, acc3 = 0.f;
    for (int k = 0; k < 512; k += 4) {
        acc0 += xr[k + 0] * Wm[(k + 0) * 16 + col];
        acc1 += xr[k + 1] * Wm[(k + 1) * 16 + col];
        acc2 += xr[k + 2] * Wm[(k + 2) * 16 + col];
        acc3 += xr[k + 3] * Wm[(k + 3) * 16 + col];
    }
    float acc = (acc0 + acc1) + (acc2 + acc3);
    __shared__ float som[8][16], sth[8][16];
    float res;
    if (isTh) {
        res = tanhf(acc + bth[col]) * PI_F;
        th_out[row * 16 + col] = res;
        sth[ty][col] = res;
    } else {
        res = fmaxf(acc + bom[col], 0.f);
        om_out[row * 16 + col] = res;
        som[ty][col] = res;
    }
    __syncthreads();
    if (t < 64){
        const int r2 = t >> 3, h = t & 7;
        const long grow = (long)blockIdx.x * 8 + r2;
        const float tt = (float)(grow & 511);
        const float o0 = som[r2][h*2], o1 = som[r2][h*2+1];
        const float t0 = sth[r2][h*2], t1 = sth[r2][h*2+1];
        float c0, s0, c1, s1;
        sincosf(o0 * tt + t0, &s0, &c0);
        sincosf(o1 * tt + t1, &s1, &c1);
        float4 rr = { c0, s0, c1, s1 };
        *(float4*)&Cph[grow * 32 + h * 4] = rr;
    }
}

// ---------------------------------------------------------------------------
// FUSED moving average over bf16 input; z>>4 selects source.
// src 0/1: residual -> row-major bf16. src 2: res^T -> VTB, trend^T -> TTB.
// ---------------------------------------------------------------------------
__global__ __launch_bounds__(256)
void movavg_all(const short* __restrict__ qpB, const short* __restrict__ kpB,
                const short* __restrict__ vpB,
                short* __restrict__ qRB, short* __restrict__ kRB,
                short* __restrict__ VTB, short* __restrict__ TTB)
{
    const int zz = blockIdx.z;
    const int src = zz >> 4, b = zz & 15;
    const int l0 = blockIdx.y * 64, c0 = blockIdx.x * 64;
    const short* XB = src == 0 ? qpB : (src == 1 ? kpB : vpB);
    short* RB = src == 0 ? qRB : kRB;
    __shared__ float sm[88][64];
    const long base = (long)b * 512 * 512 + c0;
    const int t = threadIdx.x;
    for (int i = t; i < 88 * 64; i += 256) {
        const int r = i >> 6, c = i & 63;
        int gl = l0 + r - 12;
        gl = min(max(gl, 0), 511);
        sm[r][c] = bf2f((ushort)XB[base + (long)gl * 512 + c]);
    }
    __syncthreads();
    const int tx = t & 63, ty = t >> 6;
    const int rbase = ty * 16;
    float s = 0.f;
    #pragma unroll
    for (int d = 0; d < 25; d++) s += sm[rbase + d][tx];
    const float inv = 1.f / 25.f;
    short hb[16], tb[16];
    #pragma unroll
    for (int r = 0; r < 16; r++) {
        const long l = l0 + rbase + r;
        const float ma = s * inv;
        const float x = sm[rbase + r + 12][tx];
        const float res = x - ma;
        if (src < 2) {
            RB[((long)b * 512 + l) * 512 + c0 + tx] = (short)f2bf(res);
        } else {
            hb[r] = (short)f2bf(res);
            tb[r] = (short)f2bf(ma);
        }
        if (r < 15) s += sm[rbase + r + 25][tx] - sm[rbase + r][tx];
    }
    if (src == 2) {
        const long vo = ((long)b * 512 + c0 + tx) * 512 + l0 + rbase;
        *(uint4*)&VTB[vo]     = ((uint4*)hb)[0];
        *(uint4*)&VTB[vo + 8] = ((uint4*)hb)[1];
        *(uint4*)&TTB[vo]     = ((uint4*)tb)[0];
        *(uint4*)&TTB[vo + 8] = ((uint4*)tb)[1];
    }
}

// ---------------------------------------------------------------------------
// Flash attention (r18-v5, best measured): packed bf16 scores (pk[64]),
// 8-stage pipelined, 24KB LDS, direct scalar attn store.
// ---------------------------------------------------------------------------
__global__ __launch_bounds__(256)
void flash_k(const short* __restrict__ qB, const short* __restrict__ kB,
             const short* __restrict__ vtB,
             const float* __restrict__ Cq, const float* __restrict__ Ck,
             float* __restrict__ attn, float* __restrict__ attn_out)
{
  const int bid = blockIdx.y*8 + blockIdx.x;
  const int swz = (bid & 7)*128 + (bid >> 3);
  const int z = swz >> 3; const int b = z >> 3, h = z & 7;
  const int l0 = (swz & 7) * 64;
  const int t = threadIdx.x, wave = t >> 6, lane = t & 63;
  const int lr = lane & 15, lk = lane >> 4;

  __shared__ short SH[8192];
  __shared__ float CkS[2048];
  short* Qs = SH;
  short* Ks = SH;
  short* PPs = SH;
  short* Vs = SH + 4096;

  const int sr0 = t >> 3,          skb0 = t & 7;
  const int sr1 = (t >> 3) + 32,   skb1 = t & 7;
  const int sidx0 = sr0*64 + ((skb0 ^ (sr0 & 7)) << 3);
  const int sidx1 = sr1*64 + ((skb1 ^ (sr1 & 7)) << 3);

  stage_sync<64>(qB + ((long)(b*512 + l0))*512 + h*64, 512, Qs, t);
#pragma unroll
  for (int i = 0; i < 2; i++){
    int s = t + i*256;
    ((float4*)CkS)[s] = *(const float4*)(Ck + (((long)b*512 + s)*8 + h)*4);
  }
  __syncthreads();
  bf16x8 aq[2];
#pragma unroll
  for (int kk = 0; kk < 2; kk++){
    int row = wave*16 + lr;
    aq[kk] = *(const bf16x8*)&Qs[row*64 + (((kk*4 + lk) ^ (row & 7)) << 3)];
  }
  float4 cqv[4];
#pragma unroll
  for (int r = 0; r < 4; r++){
    int row = l0 + wave*16 + lk*4 + r;
    cqv[r] = *(const float4*)(Cq + (((long)b*512 + row)*8 + h)*4);
  }

  const long kbase0 = ((long)(b*512 + sr0))*512 + h*64 + skb0*8;
  const long kbase1 = ((long)(b*512 + sr1))*512 + h*64 + skb1*8;
  uint4 pA0, pA1, pB0, pB1;
  pA0 = *(const uint4*)(kB + kbase0);
  pA1 = *(const uint4*)(kB + kbase1);
  __syncthreads();

  uint pk[64];
#pragma unroll
  for (int st = 0; st < 8; st++){
    if (st & 1){
      *(uint4*)&Ks[sidx0] = pB0; *(uint4*)&Ks[sidx1] = pB1;
      if (st < 7){
        pA0 = *(const uint4*)(kB + kbase0 + (long)(st+1)*64*512);
        pA1 = *(const uint4*)(kB + kbase1 + (long)(st+1)*64*512);
      }
    } else {
      *(uint4*)&Ks[sidx0] = pA0; *(uint4*)&Ks[sidx1] = pA1;
      if (st < 7){
        pB0 = *(const uint4*)(kB + kbase0 + (long)(st+1)*64*512);
        pB1 = *(const uint4*)(kB + kbase1 + (long)(st+1)*64*512);
      }
    }
    __syncthreads();
    f32x4 tmp[4];
#pragma unroll
    for (int nj = 0; nj < 4; nj++) tmp[nj] = (f32x4){0.f,0.f,0.f,0.f};
#pragma unroll
    for (int nj = 0; nj < 4; nj++){
      int srow = nj*16 + lr;
#pragma unroll
      for (int kk = 0; kk < 2; kk++){
        bf16x8 bh = *(const bf16x8*)&Ks[srow*64 + (((kk*4 + lk) ^ (srow & 7)) << 3)];
        tmp[nj] = __builtin_amdgcn_mfma_f32_16x16x32_bf16(aq[kk], bh, tmp[nj], 0,0,0);
      }
    }
#pragma unroll
    for (int nj = 0; nj < 4; nj++){
      int col = st*64 + nj*16 + lr;
      float4 ckv = ((float4*)CkS)[col];
#pragma unroll
      for (int r = 0; r < 4; r++){
        float mod = 0.125f*(cqv[r].x*ckv.x + cqv[r].y*ckv.y + cqv[r].z*ckv.z + cqv[r].w*ckv.w);
        tmp[nj][r] *= mod;
      }
    }
#pragma unroll
    for (int nj2 = 0; nj2 < 2; nj2++)
#pragma unroll
      for (int r = 0; r < 4; r++)
        pk[st*8 + nj2*4 + r] = (uint)f2bf(tmp[nj2*2][r]) | ((uint)f2bf(tmp[nj2*2+1][r]) << 16);
    if (st < 7) __syncthreads();
  }

  const long vbase0 = ((long)(z*64 + sr0))*512 + skb0*8;
  const long vbase1 = ((long)(z*64 + sr1))*512 + skb1*8;
  pA0 = *(const uint4*)(vtB + vbase0);
  pA1 = *(const uint4*)(vtB + vbase1);

  float mx[4] = {-INFINITY, -INFINITY, -INFINITY, -INFINITY};
#pragma unroll
  for (int g = 0; g < 16; g++)
#pragma unroll
    for (int r = 0; r < 4; r++){
      uint u = pk[g*4 + r];
      mx[r] = fmaxf(mx[r], fmaxf(bf2f((ushort)(u & 0xffffu)), bf2f((ushort)(u >> 16))));
    }
#pragma unroll
  for (int msk = 1; msk < 16; msk <<= 1)
#pragma unroll
    for (int r = 0; r < 4; r++) mx[r] = fmaxf(mx[r], __shfl_xor(mx[r], msk));
  float sme[4] = {0.f, 0.f, 0.f, 0.f};
#pragma unroll
  for (int g = 0; g < 16; g++)
#pragma unroll
    for (int r = 0; r < 4; r++){
      uint u = pk[g*4 + r];
      float e0 = __expf(bf2f((ushort)(u & 0xffffu)) - mx[r]);
      float e1 = __expf(bf2f((ushort)(u >> 16)) - mx[r]);
      sme[r] += e0 + e1;
      pk[g*4 + r] = (uint)f2bf(e0) | ((uint)f2bf(e1) << 16);
    }
#pragma unroll
  for (int msk = 1; msk < 16; msk <<= 1)
#pragma unroll
    for (int r = 0; r < 4; r++) sme[r] += __shfl_xor(sme[r], msk);
  float inv[4];
#pragma unroll
  for (int r = 0; r < 4; r++) inv[r] = 1.f / sme[r];

  f32x4 oacc[4];
#pragma unroll
  for (int nj = 0; nj < 4; nj++) oacc[nj] = (f32x4){0.f,0.f,0.f,0.f};
#pragma unroll
  for (int st = 0; st < 8; st++){
    __syncthreads();
#pragma unroll
    for (int a2 = 0; a2 < 4; a2++){
      int c = a2*16 + lr;
#pragma unroll
      for (int r = 0; r < 4; r++){
        uint u = pk[st*8 + (a2 >> 1)*4 + r];
        float e = bf2f((ushort)((a2 & 1) ? (u >> 16) : (u & 0xffffu)));
        float p = e * inv[r];
        int row = wave*16 + lk*4 + r;
        PPs[row*64 + (((c >> 3) ^ (row & 7)) << 3) + (c & 7)] = (short)f2bf(p);
        attn[((long)z*512 + l0 + row)*512 + st*64 + c] = p;
      }
    }
    if (st & 1){
      *(uint4*)&Vs[sidx0] = pB0; *(uint4*)&Vs[sidx1] = pB1;
      if (st < 7){
        pA0 = *(const uint4*)(vtB + vbase0 + (st+1)*64);
        pA1 = *(const uint4*)(vtB + vbase1 + (st+1)*64);
      }
    } else {
      *(uint4*)&Vs[sidx0] = pA0; *(uint4*)&Vs[sidx1] = pA1;
      if (st < 7){
        pB0 = *(const uint4*)(vtB + vbase0 + (st+1)*64);
        pB1 = *(const uint4*)(vtB + vbase1 + (st+1)*64);
      }
    }
    __syncthreads();
#pragma unroll
    for (int kk = 0; kk < 2; kk++){
      int prow = wave*16 + lr;
      int phys = (kk*4 + lk) ^ (prow & 7);
      bf16x8 ah = *(const bf16x8*)&PPs[prow*64 + phys*8];
#pragma unroll
      for (int nj = 0; nj < 4; nj++){
        int vrow = nj*16 + lr;
        bf16x8 bh = *(const bf16x8*)&Vs[vrow*64 + (((kk*4 + lk) ^ (vrow & 7)) << 3)];
        oacc[nj] = __builtin_amdgcn_mfma_f32_16x16x32_bf16(ah, bh, oacc[nj], 0,0,0);
      }
    }
  }
#pragma unroll
  for (int nj = 0; nj < 4; nj++)
#pragma unroll
    for (int r = 0; r < 4; r++){
      int grow = l0 + wave*16 + lk*4 + r;
      attn_out[((long)b*512 + grow)*512 + h*64 + nj*16 + lr] = oacc[nj][r];
    }
}

// ---------------------------------------------------------------------------
// Lambda conv + w, reading trend^T bf16 (TTB[(b*512+c)][l]).
// ---------------------------------------------------------------------------
__global__ __launch_bounds__(512)
void lamw_k(const short* __restrict__ TTB, const float* __restrict__ Wlam,
            const float* __restrict__ blam, const float* __restrict__ Sv,
            float* __restrict__ Wout)
{
    const int z = blockIdx.x;
    const int b = z >> 3, h = z & 7;
    __shared__ float sv[512][17];
    __shared__ float sw[448];
    const int t = threadIdx.x;
    if (t < 448) sw[t] = Wlam[t];
    const short* __restrict__ Tb = TTB + ((long)b * 512 + h * 64) * 512;
    float lam = 0.f;
    for (int ec = 0; ec < 4; ec++) {
        __syncthreads();
        #pragma unroll
        for (int j = 0; j < 16; j++)
            sv[t][j] = bf2f((ushort)Tb[(long)(ec * 16 + j) * 512 + t]);
        __syncthreads();
        #pragma unroll
        for (int dk = 0; dk < 7; dk++) {
            int r = t + dk - 3;
            r = min(max(r, 0), 511);
            #pragma unroll
            for (int j = 0; j < 16; j++)
                lam += sv[r][j] * sw[(ec * 16 + j) * 7 + dk];
        }
    }
    lam += blam[0];
    const float el = lam > 0.f ? lam : expm1f(lam);
    const float wv = 1.f / (1.f + (1.f + el) * Sv[t]);
    Wout[(long)z * 512 + t] = wv;
}

// ---------------------------------------------------------------------------
__global__ __launch_bounds__(256)
void pen1_k(const float* __restrict__ qom, const float* __restrict__ kom,
            const float* __restrict__ qth, const float* __restrict__ kth,
            float* __restrict__ partials)
{
    const long tid = (long)blockIdx.x * 256 + threadIdx.x;
    float om = 0.f, th = 0.f;
    for (long i = tid; i < 262144; i += 65536) {
        const float* om_arr = (i < 131072) ? qom : kom;
        const float* th_arr = (i < 131072) ? qth : kth;
        const long j = i & 131071;
        const float x = th_arr[j];
        th += x * x;
        const int l = (int)((j >> 4) & 511);
        if (l < 511) {
            const float d = om_arr[j + 16] - om_arr[j];
            om += d * d;
        }
    }
    __shared__ float som[256], sth[256];
    som[threadIdx.x] = om; sth[threadIdx.x] = th;
    __syncthreads();
    for (int o = 128; o; o >>= 1) {
        if (threadIdx.x < o) {
            som[threadIdx.x] += som[threadIdx.x + o];
            sth[threadIdx.x] += sth[threadIdx.x + o];
        }
        __syncthreads();
    }
    if (threadIdx.x == 0) {
        partials[blockIdx.x] = som[0];
        partials[256 + blockIdx.x] = sth[0];
    }
}

__global__ __launch_bounds__(256)
void pen2_k(const float* __restrict__ partials, float* __restrict__ om_out,
            float* __restrict__ th_out)
{
    __shared__ float som[256], sth[256];
    const int t = threadIdx.x;
    som[t] = partials[t]; sth[t] = partials[256 + t];
    __syncthreads();
    for (int o = 128; o; o >>= 1) {
        if (t < o) { som[t] += som[t + o]; sth[t] += sth[t + o]; }
        __syncthreads();
    }
    if (t == 0) { *om_out = som[0]; *th_out = sth[0]; }
}

// ---------------------------------------------------------------------------
extern "C" void kernel_launch(void* const* d_in, const int* in_sizes, int n_in,
                              void* d_out_v, int out_size, void* d_ws, size_t ws_size,
                              hipStream_t stream)
{
    const float* queries = (const float*)d_in[0];
    const float* keys    = (const float*)d_in[1];
    const float* values  = (const float*)d_in[2];
    const float* Wq  = (const float*)d_in[3];  const float* bq  = (const float*)d_in[4];
    const float* Wk  = (const float*)d_in[5];  const float* bk  = (const float*)d_in[6];
    const float* Wv  = (const float*)d_in[7];  const float* bv  = (const float*)d_in[8];
    const float* Wqo = (const float*)d_in[9];  const float* bqo = (const float*)d_in[10];
    const float* Wko = (const float*)d_in[11]; const float* bko = (const float*)d_in[12];
    const float* Wqt = (const float*)d_in[13]; const float* bqt = (const float*)d_in[14];
    const float* Wkt = (const float*)d_in[15]; const float* bkt = (const float*)d_in[16];
    const float* Wo  = (const float*)d_in[17]; const float* bo  = (const float*)d_in[18];
    const float* Wlam= (const float*)d_in[19]; const float* blam= (const float*)d_in[20];
    const float* U   = (const float*)d_in[21]; const float* Sv  = (const float*)d_in[22];

    float* out = (float*)d_out_v;
    float* W   = (float*)d_ws;

    short* qpB = (short*)W;
    short* kpB = (short*)(W + 4194304);
    short* vpB = (short*)(W + 8388608);
    float* attn_out = W + 4194304;
    short* TTB = (short*)(W + 12582912);
    short* R1  = (short*)(W + 16777216);
    short* qresB = R1;
    short* kresB = R1 + 4194304;
    short* vtB   = R1 + 8388608;
    short* aoB = kresB;
    short* T1tB = (short*)W;
    short* UB  = (short*)(W + 8388608);
    short* UtB = UB + 262144;
    float* q_om = W + 29360128;
    float* k_om = q_om + 131072;
    float* q_th = k_om + 131072;
    float* k_th = q_th + 131072;
    float* Cq   = k_th + 131072;
    float* Ck   = Cq + 262144;
    float* wbuf = Ck + 262144;
    float* partials = wbuf + 65536;
    short* wsp = (short*)(W + 30475264);
    short* WqB = wsp;
    short* WkB = wsp + 262144;
    short* WvB = wsp + 524288;
    short* WoB = wsp + 786432;

    float* attn = out + ATTN_OFF;
    dim3 blk(256);

    // 0. pre-converts (weights only; activations convert in-GEMM)
    wconv_t<<<dim3(8,8,4), blk, 0, stream>>>(Wq, Wk, Wv, Wo, WqB, WkB, WvB, WoB);

    // 1. fused QKV projection, A staged from f32 with in-staging cvt (EPI 6)
    mgemm<128,128,true,true,6><<<dim3(4,64,3), blk, 0, stream>>>(
        512, nullptr, queries, keys, values, 512, 0, 0, WqB, 0, 0,
        nullptr, 512, 0, 0,
        bq, bk, bv, nullptr, qpB, 1);

    // 2. fused omega/theta projections + phase tables
    skinny_k<<<dim3(1024,2), blk, 0, stream>>>(queries, keys,
        Wqo, bqo, Wqt, bqt, Wko, bko, Wkt, bkt,
        q_om, q_th, Cq, k_om, k_th, Ck);

    // 3. fused series decomposition
    movavg_all<<<dim3(8,8,48), blk, 0, stream>>>(qpB, kpB, vpB,
        qresB, kresB, vtB, TTB);

    // 3.5 U -> bf16 (both layouts)
    uconv<<<dim3(8,8), blk, 0, stream>>>(U, UB, UtB);

    // 4. fused scores+softmax+attn-write+PV (r18-v5)
    flash_k<<<dim3(8,128), blk, 0, stream>>>(qresB, kresB, vtB, Cq, Ck, attn, attn_out);

    // 5. lambda conv -> w (reads trend^T bf16)
    lamw_k<<<dim3(128), dim3(512), 0, stream>>>(TTB, Wlam, blam, Sv, wbuf);

    // 6. T1t[e][i] = (sum_l trend[l][e] U[l][i]) * w[i] -> bf16 (EPI 4)
    mgemm<64,128,false,false,4><<<dim3(4,1,128), blk, 0, stream>>>(
        512, TTB, nullptr, nullptr, nullptr, 512, 262144, 32768, UtB, 0, 0,
        nullptr, 512, 262144, 32768,
        nullptr, nullptr, nullptr, wbuf, T1tB, 8);

    // 7. aoB(bf16) = attn_out(f32) + U @ T1  (EPI 5)
    mgemm<128,64,false,false,5><<<dim3(1,4,128), blk, 0, stream>>>(
        512, UB, nullptr, nullptr, nullptr, 512, 0, 0, T1tB, 262144, 32768,
        attn_out, 512, 262144, 64,
        nullptr, nullptr, nullptr, nullptr, aoB, 8);

    // 8. out projection (EPI 1)
    mgemm<64,128,false,false,1><<<dim3(4,128,1), blk, 0, stream>>>(
        512, aoB, nullptr, nullptr, nullptr, 512, 0, 0, WoB, 0, 0,
        out, 512, 0, 0,
        bo, nullptr, nullptr, nullptr, nullptr, 1);

    // 9. penalties
    pen1_k<<<dim3(256), blk, 0, stream>>>(q_om, k_om, q_th, k_th, partials);
    pen2_k<<<dim3(1), blk, 0, stream>>>(partials, out + OM_OFF, out + TH_OFF);
}

// Round 21
// 222.034 us; speedup vs baseline: 1.0218x; 1.0191x over previous
//
#include <hip/hip_runtime.h>
#include <math.h>

// B=16, L=512, D_MODEL=512, H=8, M=2, E=64, KMA=25, KLAM=7
// Outputs (f32, concat): out (16,512,512) | attn (16,8,512,512) | om_pen | th_pen
// Single-bf16 arithmetic everywhere.

#define PI_F 3.14159265358979323846f

typedef __attribute__((ext_vector_type(8))) short bf16x8;
typedef __attribute__((ext_vector_type(4))) float f32x4;

static constexpr long ATTN_OFF = 4194304;
static constexpr long OM_OFF   = 37748736;
static constexpr long TH_OFF   = 37748737;

// ---------------------------------------------------------------------------
__device__ __forceinline__ ushort f2bf(float f){
  uint u = __float_as_uint(f);
  u += 0x7fffu + ((u >> 16) & 1u);
  return (ushort)(u >> 16);
}
__device__ __forceinline__ float bf2f(ushort h){
  return __uint_as_float((uint)h << 16);
}
__device__ __forceinline__ uint4 cvt8s(const float* f){
  ushort h[8];
#pragma unroll
  for (int j = 0; j < 8; j++) h[j] = f2bf(f[j]);
  uint4 H;
  H.x = (uint)h[0] | ((uint)h[1] << 16); H.y = (uint)h[2] | ((uint)h[3] << 16);
  H.z = (uint)h[4] | ((uint)h[5] << 16); H.w = (uint)h[6] | ((uint)h[7] << 16);
  return H;
}

// ---------------------------------------------------------------------------
// Single-stream async LDS staging: dest lane-linear (p*16B), swizzle moved to
// global source via involution kb = (p&7)^(row&7)  (rule #21).
// ---------------------------------------------------------------------------
template<int ROWS>
__device__ __forceinline__ void stage_sb(const short* __restrict__ G, int ldk,
                                         short* dst, int t){
#pragma unroll
  for (int i = 0; i < ROWS*8/256; i++){
    int p = t + i*256;
    int row = p >> 3;
    int kb = (p & 7) ^ (row & 7);
    __builtin_amdgcn_global_load_lds(
        (const __attribute__((address_space(1))) uint*)(G + (long)row*ldk + kb*8),
        (__attribute__((address_space(3))) uint*)(dst + (long)p*8), 16, 0, 0);
  }
}

// sync single-stream stage (register round-trip) — flash Q
template<int ROWS>
__device__ __forceinline__ void stage_sync(const short* __restrict__ G, int ldk,
                                           short* dst, int t){
#pragma unroll
  for (int i = 0; i < ROWS*8/256; i++){
    int p = t + i*256;
    int row = p >> 3, kb = p & 7;
    uint4 v = *(const uint4*)(G + (long)row*ldk + kb*8);
    *(uint4*)&dst[row*64 + ((kb ^ (row & 7)) << 3)] = v;
  }
}

// ---------------------------------------------------------------------------
// MFMA GEMM, single bf16: C = epi(A @ B). A,B pre-converted bf16 [row][k].
// EPI: 1=+bias->f32  4=*wcol->bf16  5=Cf32+= ->bf16  6=+bias->bf16
// ---------------------------------------------------------------------------
template<int BM,int BN,bool QKV,int EPI>
__global__ __launch_bounds__(256)
void mgemm(int K,
  const short* __restrict__ AB, int lda, long sAb, long sAh,
  const short* __restrict__ BB, long sBb, long sBh,
  float* __restrict__ C, int ldc, long sCb, long sCh,
  const float* __restrict__ bias, const float* __restrict__ bias1, const float* __restrict__ bias2,
  const float* __restrict__ wcolp, short* __restrict__ CB, int Hdiv)
{
  __shared__ short As[BM*64], Bs[BN*64];
  constexpr int WMT = BM/2, WNT = BN/2;
  constexpr int FM = WMT/16, FN = WNT/16;

  const int z = blockIdx.z;
  const int zb = z / Hdiv, zh = z % Hdiv;
  const short* Ab = AB;
  const short* Bb = BB;
  float* Cb = C;
  short* Cbb = CB;
  if constexpr (QKV){
    Ab += (long)zb*4194304;
    if constexpr (EPI >= 4) Cbb += (long)zb*4194304;
  } else {
    Ab += (long)zb*sAb + (long)zh*sAh;
    Bb += (long)zb*sBb + (long)zh*sBh;
    if (C) Cb += (long)zb*sCb + (long)zh*sCh;
    if constexpr (EPI >= 4) Cbb += (long)zb*sCb + (long)zh*sCh;
  }

  const int t = threadIdx.x;
  const int m0 = blockIdx.y*BM, n0 = blockIdx.x*BN;
  const int wave = t >> 6, lane = t & 63;
  const int wr = wave >> 1, wc = wave & 1;
  const int lr = lane & 15, lk = lane >> 4;

  f32x4 acc[FM][FN];
#pragma unroll
  for (int mi = 0; mi < FM; mi++)
#pragma unroll
    for (int nj = 0; nj < FN; nj++) acc[mi][nj] = (f32x4){0.f, 0.f, 0.f, 0.f};

  for (int k0 = 0; k0 < K; k0 += 64){
    stage_sb<BM>(Ab + (long)m0*lda + k0, lda, As, t);
    stage_sb<BN>(Bb + (long)n0*K + k0, K, Bs, t);
    __syncthreads();
#pragma unroll
    for (int kk = 0; kk < 2; kk++){
      bf16x8 ah[FM], bh[FN];
#pragma unroll
      for (int mi = 0; mi < FM; mi++){
        int row = wr*WMT + mi*16 + lr;
        ah[mi] = *(const bf16x8*)&As[row*64 + (((kk*4 + lk) ^ (row & 7)) << 3)];
      }
#pragma unroll
      for (int nj = 0; nj < FN; nj++){
        int col = wc*WNT + nj*16 + lr;
        bh[nj] = *(const bf16x8*)&Bs[col*64 + (((kk*4 + lk) ^ (col & 7)) << 3)];
      }
#pragma unroll
      for (int mi = 0; mi < FM; mi++)
#pragma unroll
        for (int nj = 0; nj < FN; nj++)
          acc[mi][nj] = __builtin_amdgcn_mfma_f32_16x16x32_bf16(ah[mi], bh[nj], acc[mi][nj], 0, 0, 0);
    }
    __syncthreads();
  }

  const float* wz = nullptr;
  if constexpr (EPI == 4) wz = wcolp + (long)z*512;
  const float* bp = bias;
  if constexpr (QKV) bp = (zb == 0) ? bias : ((zb == 1) ? bias1 : bias2);

#pragma unroll
  for (int mi = 0; mi < FM; mi++){
#pragma unroll
    for (int r = 0; r < 4; r++){
      int grow = m0 + wr*WMT + mi*16 + lk*4 + r;
#pragma unroll
      for (int nj = 0; nj < FN; nj++){
        int gcol = n0 + wc*WNT + nj*16 + lr;
        float v = acc[mi][nj][r];
        if constexpr (EPI == 1 || EPI == 6) v += bp[gcol];
        if constexpr (EPI == 5) v += Cb[(long)grow*ldc + gcol];
        if constexpr (EPI == 4) v *= wz[gcol];
        if constexpr (EPI >= 4) Cbb[(long)grow*ldc + gcol] = (short)f2bf(v);
        else                    Cb[(long)grow*ldc + gcol] = v;
      }
    }
  }
}

// ---------------------------------------------------------------------------
// Weight transpose + bf16 convert (Wq,Wk,Wv,Wo -> [n][k])
// ---------------------------------------------------------------------------
__global__ __launch_bounds__(256)
void wconv_t(const float* __restrict__ W0, const float* __restrict__ W1,
             const float* __restrict__ W2, const float* __restrict__ W3,
             short* B0, short* B1, short* B2, short* B3)
{
  const float* W; short* Bp;
  switch (blockIdx.z){
    case 0:  W = W0; Bp = B0; break;
    case 1:  W = W1; Bp = B1; break;
    case 2:  W = W2; Bp = B2; break;
    default: W = W3; Bp = B3; break;
  }
  __shared__ float s[64][65];
  const int r0 = blockIdx.y*64, c0 = blockIdx.x*64;
  const int t = threadIdx.x;
#pragma unroll
  for (int i = 0; i < 4; i++){
    int idx = t + i*256;
    int r = idx >> 4, c4 = (idx & 15)*4;
    float4 v = *(const float4*)(W + (long)(r0 + r)*512 + c0 + c4);
    s[r][c4+0] = v.x; s[r][c4+1] = v.y; s[r][c4+2] = v.z; s[r][c4+3] = v.w;
  }
  __syncthreads();
#pragma unroll
  for (int i = 0; i < 2; i++){
    int p = t + i*256;
    int n = p >> 3, kb = p & 7;
    float f[8];
#pragma unroll
    for (int j = 0; j < 8; j++) f[j] = s[kb*8 + j][n];
    *(uint4*)&Bp[(long)(c0 + n)*512 + r0 + kb*8] = cvt8s(f);
  }
}

// ---------------------------------------------------------------------------
// U -> bf16 in BOTH layouts: UB row-major [l][i], UtB [i][l]
// ---------------------------------------------------------------------------
__global__ __launch_bounds__(256)
void uconv(const float* __restrict__ U, short* __restrict__ UB, short* __restrict__ UtB)
{
  __shared__ float s[64][65];
  const int r0 = blockIdx.y*64, c0 = blockIdx.x*64;
  const int t = threadIdx.x;
#pragma unroll
  for (int i = 0; i < 4; i++){
    int idx = t + i*256;
    int r = idx >> 4, c4 = (idx & 15)*4;
    float4 v = *(const float4*)(U + (long)(r0 + r)*512 + c0 + c4);
    s[r][c4+0] = v.x; s[r][c4+1] = v.y; s[r][c4+2] = v.z; s[r][c4+3] = v.w;
  }
  __syncthreads();
#pragma unroll
  for (int i = 0; i < 2; i++){
    int p = t + i*256;
    int rr = p >> 3, kb = p & 7;
    float f[8];
#pragma unroll
    for (int j = 0; j < 8; j++) f[j] = s[rr][kb*8 + j];
    *(uint4*)&UB[(long)(r0 + rr)*512 + c0 + kb*8] = cvt8s(f);
  }
#pragma unroll
  for (int i = 0; i < 2; i++){
    int p = t + i*256;
    int n = p >> 3, kb = p & 7;
    float f[8];
#pragma unroll
    for (int j = 0; j < 8; j++) f[j] = s[kb*8 + j][n];
    *(uint4*)&UtB[(long)(c0 + n)*512 + r0 + kb*8] = cvt8s(f);
  }
}

// ---------------------------------------------------------------------------
// Activation pre-convert: q,k,v -> bf16 row-major
// ---------------------------------------------------------------------------
__global__ __launch_bounds__(256)
void acvt(const float* __restrict__ q, const float* __restrict__ k,
          const float* __restrict__ v, short* __restrict__ base)
{
  long g = (long)blockIdx.x*256 + threadIdx.x;
  if (g >= 1572864) return;
  long idx = g & 524287; int sel = (int)(g >> 19);
  const float* src = sel == 0 ? q : (sel == 1 ? k : v);
  short* Bp = base + (long)sel*4194304;
  float f[8];
  *(float4*)&f[0] = *(const float4*)(src + idx*8);
  *(float4*)&f[4] = *(const float4*)(src + idx*8 + 4);
  *(uint4*)&Bp[idx*8] = cvt8s(f);
}

// ---------------------------------------------------------------------------
// Fused skinny projection + phases; blockIdx.y selects (q|k).
// ---------------------------------------------------------------------------
__global__ __launch_bounds__(256)
void skinny_k(const float* __restrict__ Xq, const float* __restrict__ Xk,
              const float* __restrict__ Wqo, const float* __restrict__ bqo,
              const float* __restrict__ Wqt, const float* __restrict__ bqt,
              const float* __restrict__ Wko, const float* __restrict__ bko,
              const float* __restrict__ Wkt, const float* __restrict__ bkt,
              float* __restrict__ q_om, float* __restrict__ q_th, float* __restrict__ Cq,
              float* __restrict__ k_om, float* __restrict__ k_th, float* __restrict__ Ck)
{
    const int sel = blockIdx.y;
    const float* X   = sel ? Xk  : Xq;
    const float* Wom = sel ? Wko : Wqo;  const float* bom = sel ? bko : bqo;
    const float* Wth = sel ? Wkt : Wqt;  const float* bth = sel ? bkt : bqt;
    float* om_out = sel ? k_om : q_om;
    float* th_out = sel ? k_th : q_th;
    float* Cph    = sel ? Ck   : Cq;

    const int t = threadIdx.x;
    const int tx = t & 31, ty = t >> 5;
    const long row = (long)blockIdx.x * 8 + ty;
    const int col = tx & 15;
    const bool isTh = tx >= 16;
    const float* __restrict__ Wm = isTh ? Wth : Wom;
    const float* __restrict__ xr = X + row * 512;
    float acc0 = 0.f, acc1 = 0.f, acc2 = 0.f, acc3 = 0.f;
    for (int k = 0; k < 512; k += 4) {
        acc0 += xr[k + 0] * Wm[(k + 0) * 16 + col];
        acc1 += xr[k + 1] * Wm[(k + 1) * 16 + col];
        acc2 += xr[k + 2] * Wm[(k + 2) * 16 + col];
        acc3 += xr[k + 3] * Wm[(k + 3) * 16 + col];
    }
    float acc = (acc0 + acc1) + (acc2 + acc3);
    __shared__ float som[8][16], sth[8][16];
    float res;
    if (isTh) {
        res = tanhf(acc + bth[col]) * PI_F;
        th_out[row * 16 + col] = res;
        sth[ty][col] = res;
    } else {
        res = fmaxf(acc + bom[col], 0.f);
        om_out[row * 16 + col] = res;
        som[ty][col] = res;
    }
    __syncthreads();
    if (t < 64){
        const int r2 = t >> 3, h = t & 7;
        const long grow = (long)blockIdx.x * 8 + r2;
        const float tt = (float)(grow & 511);
        const float o0 = som[r2][h*2], o1 = som[r2][h*2+1];
        const float t0 = sth[r2][h*2], t1 = sth[r2][h*2+1];
        float c0, s0, c1, s1;
        sincosf(o0 * tt + t0, &s0, &c0);
        sincosf(o1 * tt + t1, &s1, &c1);
        float4 rr = { c0, s0, c1, s1 };
        *(float4*)&Cph[grow * 32 + h * 4] = rr;
    }
}

// ---------------------------------------------------------------------------
// FUSED moving average over bf16 input; z>>4 selects source.
// src 0/1: residual -> row-major bf16. src 2: res^T -> VTB, trend^T -> TTB.
// ---------------------------------------------------------------------------
__global__ __launch_bounds__(256)
void movavg_all(const short* __restrict__ qpB, const short* __restrict__ kpB,
                const short* __restrict__ vpB,
                short* __restrict__ qRB, short* __restrict__ kRB,
                short* __restrict__ VTB, short* __restrict__ TTB)
{
    const int zz = blockIdx.z;
    const int src = zz >> 4, b = zz & 15;
    const int l0 = blockIdx.y * 64, c0 = blockIdx.x * 64;
    const short* XB = src == 0 ? qpB : (src == 1 ? kpB : vpB);
    short* RB = src == 0 ? qRB : kRB;
    __shared__ float sm[88][64];
    const long base = (long)b * 512 * 512 + c0;
    const int t = threadIdx.x;
    for (int i = t; i < 88 * 64; i += 256) {
        const int r = i >> 6, c = i & 63;
        int gl = l0 + r - 12;
        gl = min(max(gl, 0), 511);
        sm[r][c] = bf2f((ushort)XB[base + (long)gl * 512 + c]);
    }
    __syncthreads();
    const int tx = t & 63, ty = t >> 6;
    const int rbase = ty * 16;
    float s = 0.f;
    #pragma unroll
    for (int d = 0; d < 25; d++) s += sm[rbase + d][tx];
    const float inv = 1.f / 25.f;
    short hb[16], tb[16];
    #pragma unroll
    for (int r = 0; r < 16; r++) {
        const long l = l0 + rbase + r;
        const float ma = s * inv;
        const float x = sm[rbase + r + 12][tx];
        const float res = x - ma;
        if (src < 2) {
            RB[((long)b * 512 + l) * 512 + c0 + tx] = (short)f2bf(res);
        } else {
            hb[r] = (short)f2bf(res);
            tb[r] = (short)f2bf(ma);
        }
        if (r < 15) s += sm[rbase + r + 25][tx] - sm[rbase + r][tx];
    }
    if (src == 2) {
        const long vo = ((long)b * 512 + c0 + tx) * 512 + l0 + rbase;
        *(uint4*)&VTB[vo]     = ((uint4*)hb)[0];
        *(uint4*)&VTB[vo + 8] = ((uint4*)hb)[1];
        *(uint4*)&TTB[vo]     = ((uint4*)tb)[0];
        *(uint4*)&TTB[vo + 8] = ((uint4*)tb)[1];
    }
}

// ---------------------------------------------------------------------------
// Flash attention (r18-v5, best measured): packed bf16 scores (pk[64]),
// 8-stage pipelined, 24KB LDS, direct scalar attn store.
// ---------------------------------------------------------------------------
__global__ __launch_bounds__(256)
void flash_k(const short* __restrict__ qB, const short* __restrict__ kB,
             const short* __restrict__ vtB,
             const float* __restrict__ Cq, const float* __restrict__ Ck,
             float* __restrict__ attn, float* __restrict__ attn_out)
{
  const int bid = blockIdx.y*8 + blockIdx.x;
  const int swz = (bid & 7)*128 + (bid >> 3);
  const int z = swz >> 3; const int b = z >> 3, h = z & 7;
  const int l0 = (swz & 7) * 64;
  const int t = threadIdx.x, wave = t >> 6, lane = t & 63;
  const int lr = lane & 15, lk = lane >> 4;

  __shared__ short SH[8192];
  __shared__ float CkS[2048];
  short* Qs = SH;
  short* Ks = SH;
  short* PPs = SH;
  short* Vs = SH + 4096;

  const int sr0 = t >> 3,          skb0 = t & 7;
  const int sr1 = (t >> 3) + 32,   skb1 = t & 7;
  const int sidx0 = sr0*64 + ((skb0 ^ (sr0 & 7)) << 3);
  const int sidx1 = sr1*64 + ((skb1 ^ (sr1 & 7)) << 3);

  stage_sync<64>(qB + ((long)(b*512 + l0))*512 + h*64, 512, Qs, t);
#pragma unroll
  for (int i = 0; i < 2; i++){
    int s = t + i*256;
    ((float4*)CkS)[s] = *(const float4*)(Ck + (((long)b*512 + s)*8 + h)*4);
  }
  __syncthreads();
  bf16x8 aq[2];
#pragma unroll
  for (int kk = 0; kk < 2; kk++){
    int row = wave*16 + lr;
    aq[kk] = *(const bf16x8*)&Qs[row*64 + (((kk*4 + lk) ^ (row & 7)) << 3)];
  }
  float4 cqv[4];
#pragma unroll
  for (int r = 0; r < 4; r++){
    int row = l0 + wave*16 + lk*4 + r;
    cqv[r] = *(const float4*)(Cq + (((long)b*512 + row)*8 + h)*4);
  }

  const long kbase0 = ((long)(b*512 + sr0))*512 + h*64 + skb0*8;
  const long kbase1 = ((long)(b*512 + sr1))*512 + h*64 + skb1*8;
  uint4 pA0, pA1, pB0, pB1;
  pA0 = *(const uint4*)(kB + kbase0);
  pA1 = *(const uint4*)(kB + kbase1);
  __syncthreads();

  uint pk[64];
#pragma unroll
  for (int st = 0; st < 8; st++){
    if (st & 1){
      *(uint4*)&Ks[sidx0] = pB0; *(uint4*)&Ks[sidx1] = pB1;
      if (st < 7){
        pA0 = *(const uint4*)(kB + kbase0 + (long)(st+1)*64*512);
        pA1 = *(const uint4*)(kB + kbase1 + (long)(st+1)*64*512);
      }
    } else {
      *(uint4*)&Ks[sidx0] = pA0; *(uint4*)&Ks[sidx1] = pA1;
      if (st < 7){
        pB0 = *(const uint4*)(kB + kbase0 + (long)(st+1)*64*512);
        pB1 = *(const uint4*)(kB + kbase1 + (long)(st+1)*64*512);
      }
    }
    __syncthreads();
    f32x4 tmp[4];
#pragma unroll
    for (int nj = 0; nj < 4; nj++) tmp[nj] = (f32x4){0.f,0.f,0.f,0.f};
#pragma unroll
    for (int nj = 0; nj < 4; nj++){
      int srow = nj*16 + lr;
#pragma unroll
      for (int kk = 0; kk < 2; kk++){
        bf16x8 bh = *(const bf16x8*)&Ks[srow*64 + (((kk*4 + lk) ^ (srow & 7)) << 3)];
        tmp[nj] = __builtin_amdgcn_mfma_f32_16x16x32_bf16(aq[kk], bh, tmp[nj], 0,0,0);
      }
    }
#pragma unroll
    for (int nj = 0; nj < 4; nj++){
      int col = st*64 + nj*16 + lr;
      float4 ckv = ((float4*)CkS)[col];
#pragma unroll
      for (int r = 0; r < 4; r++){
        float mod = 0.125f*(cqv[r].x*ckv.x + cqv[r].y*ckv.y + cqv[r].z*ckv.z + cqv[r].w*ckv.w);
        tmp[nj][r] *= mod;
      }
    }
#pragma unroll
    for (int nj2 = 0; nj2 < 2; nj2++)
#pragma unroll
      for (int r = 0; r < 4; r++)
        pk[st*8 + nj2*4 + r] = (uint)f2bf(tmp[nj2*2][r]) | ((uint)f2bf(tmp[nj2*2+1][r]) << 16);
    if (st < 7) __syncthreads();
  }

  const long vbase0 = ((long)(z*64 + sr0))*512 + skb0*8;
  const long vbase1 = ((long)(z*64 + sr1))*512 + skb1*8;
  pA0 = *(const uint4*)(vtB + vbase0);
  pA1 = *(const uint4*)(vtB + vbase1);

  float mx[4] = {-INFINITY, -INFINITY, -INFINITY, -INFINITY};
#pragma unroll
  for (int g = 0; g < 16; g++)
#pragma unroll
    for (int r = 0; r < 4; r++){
      uint u = pk[g*4 + r];
      mx[r] = fmaxf(mx[r], fmaxf(bf2f((ushort)(u & 0xffffu)), bf2f((ushort)(u >> 16))));
    }
#pragma unroll
  for (int msk = 1; msk < 16; msk <<= 1)
#pragma unroll
    for (int r = 0; r < 4; r++) mx[r] = fmaxf(mx[r], __shfl_xor(mx[r], msk));
  float sme[4] = {0.f, 0.f, 0.f, 0.f};
#pragma unroll
  for (int g = 0; g < 16; g++)
#pragma unroll
    for (int r = 0; r < 4; r++){
      uint u = pk[g*4 + r];
      float e0 = __expf(bf2f((ushort)(u & 0xffffu)) - mx[r]);
      float e1 = __expf(bf2f((ushort)(u >> 16)) - mx[r]);
      sme[r] += e0 + e1;
      pk[g*4 + r] = (uint)f2bf(e0) | ((uint)f2bf(e1) << 16);
    }
#pragma unroll
  for (int msk = 1; msk < 16; msk <<= 1)
#pragma unroll
    for (int r = 0; r < 4; r++) sme[r] += __shfl_xor(sme[r], msk);
  float inv[4];
#pragma unroll
  for (int r = 0; r < 4; r++) inv[r] = 1.f / sme[r];

  f32x4 oacc[4];
#pragma unroll
  for (int nj = 0; nj < 4; nj++) oacc[nj] = (f32x4){0.f,0.f,0.f,0.f};
#pragma unroll
  for (int st = 0; st < 8; st++){
    __syncthreads();
#pragma unroll
    for (int a2 = 0; a2 < 4; a2++){
      int c = a2*16 + lr;
#pragma unroll
      for (int r = 0; r < 4; r++){
        uint u = pk[st*8 + (a2 >> 1)*4 + r];
        float e = bf2f((ushort)((a2 & 1) ? (u >> 16) : (u & 0xffffu)));
        float p = e * inv[r];
        int row = wave*16 + lk*4 + r;
        PPs[row*64 + (((c >> 3) ^ (row & 7)) << 3) + (c & 7)] = (short)f2bf(p);
        attn[((long)z*512 + l0 + row)*512 + st*64 + c] = p;
      }
    }
    if (st & 1){
      *(uint4*)&Vs[sidx0] = pB0; *(uint4*)&Vs[sidx1] = pB1;
      if (st < 7){
        pA0 = *(const uint4*)(vtB + vbase0 + (st+1)*64);
        pA1 = *(const uint4*)(vtB + vbase1 + (st+1)*64);
      }
    } else {
      *(uint4*)&Vs[sidx0] = pA0; *(uint4*)&Vs[sidx1] = pA1;
      if (st < 7){
        pB0 = *(const uint4*)(vtB + vbase0 + (st+1)*64);
        pB1 = *(const uint4*)(vtB + vbase1 + (st+1)*64);
      }
    }
    __syncthreads();
#pragma unroll
    for (int kk = 0; kk < 2; kk++){
      int prow = wave*16 + lr;
      int phys = (kk*4 + lk) ^ (prow & 7);
      bf16x8 ah = *(const bf16x8*)&PPs[prow*64 + phys*8];
#pragma unroll
      for (int nj = 0; nj < 4; nj++){
        int vrow = nj*16 + lr;
        bf16x8 bh = *(const bf16x8*)&Vs[vrow*64 + (((kk*4 + lk) ^ (vrow & 7)) << 3)];
        oacc[nj] = __builtin_amdgcn_mfma_f32_16x16x32_bf16(ah, bh, oacc[nj], 0,0,0);
      }
    }
  }
#pragma unroll
  for (int nj = 0; nj < 4; nj++)
#pragma unroll
    for (int r = 0; r < 4; r++){
      int grow = l0 + wave*16 + lk*4 + r;
      attn_out[((long)b*512 + grow)*512 + h*64 + nj*16 + lr] = oacc[nj][r];
    }
}

// ---------------------------------------------------------------------------
// Lambda conv + w, reading trend^T bf16 (TTB[(b*512+c)][l]).
// ---------------------------------------------------------------------------
__global__ __launch_bounds__(512)
void lamw_k(const short* __restrict__ TTB, const float* __restrict__ Wlam,
            const float* __restrict__ blam, const float* __restrict__ Sv,
            float* __restrict__ Wout)
{
    const int z = blockIdx.x;
    const int b = z >> 3, h = z & 7;
    __shared__ float sv[512][17];
    __shared__ float sw[448];
    const int t = threadIdx.x;
    if (t < 448) sw[t] = Wlam[t];
    const short* __restrict__ Tb = TTB + ((long)b * 512 + h * 64) * 512;
    float lam = 0.f;
    for (int ec = 0; ec < 4; ec++) {
        __syncthreads();
        #pragma unroll
        for (int j = 0; j < 16; j++)
            sv[t][j] = bf2f((ushort)Tb[(long)(ec * 16 + j) * 512 + t]);
        __syncthreads();
        #pragma unroll
        for (int dk = 0; dk < 7; dk++) {
            int r = t + dk - 3;
            r = min(max(r, 0), 511);
            #pragma unroll
            for (int j = 0; j < 16; j++)
                lam += sv[r][j] * sw[(ec * 16 + j) * 7 + dk];
        }
    }
    lam += blam[0];
    const float el = lam > 0.f ? lam : expm1f(lam);
    const float wv = 1.f / (1.f + (1.f + el) * Sv[t]);
    Wout[(long)z * 512 + t] = wv;
}

// ---------------------------------------------------------------------------
__global__ __launch_bounds__(256)
void pen1_k(const float* __restrict__ qom, const float* __restrict__ kom,
            const float* __restrict__ qth, const float* __restrict__ kth,
            float* __restrict__ partials)
{
    const long tid = (long)blockIdx.x * 256 + threadIdx.x;
    float om = 0.f, th = 0.f;
    for (long i = tid; i < 262144; i += 65536) {
        const float* om_arr = (i < 131072) ? qom : kom;
        const float* th_arr = (i < 131072) ? qth : kth;
        const long j = i & 131071;
        const float x = th_arr[j];
        th += x * x;
        const int l = (int)((j >> 4) & 511);
        if (l < 511) {
            const float d = om_arr[j + 16] - om_arr[j];
            om += d * d;
        }
    }
    __shared__ float som[256], sth[256];
    som[threadIdx.x] = om; sth[threadIdx.x] = th;
    __syncthreads();
    for (int o = 128; o; o >>= 1) {
        if (threadIdx.x < o) {
            som[threadIdx.x] += som[threadIdx.x + o];
            sth[threadIdx.x] += sth[threadIdx.x + o];
        }
        __syncthreads();
    }
    if (threadIdx.x == 0) {
        partials[blockIdx.x] = som[0];
        partials[256 + blockIdx.x] = sth[0];
    }
}

__global__ __launch_bounds__(256)
void pen2_k(const float* __restrict__ partials, float* __restrict__ om_out,
            float* __restrict__ th_out)
{
    __shared__ float som[256], sth[256];
    const int t = threadIdx.x;
    som[t] = partials[t]; sth[t] = partials[256 + t];
    __syncthreads();
    for (int o = 128; o; o >>= 1) {
        if (t < o) { som[t] += som[t + o]; sth[t] += sth[t + o]; }
        __syncthreads();
    }
    if (t == 0) { *om_out = som[0]; *th_out = sth[0]; }
}

// ---------------------------------------------------------------------------
extern "C" void kernel_launch(void* const* d_in, const int* in_sizes, int n_in,
                              void* d_out_v, int out_size, void* d_ws, size_t ws_size,
                              hipStream_t stream)
{
    const float* queries = (const float*)d_in[0];
    const float* keys    = (const float*)d_in[1];
    const float* values  = (const float*)d_in[2];
    const float* Wq  = (const float*)d_in[3];  const float* bq  = (const float*)d_in[4];
    const float* Wk  = (const float*)d_in[5];  const float* bk  = (const float*)d_in[6];
    const float* Wv  = (const float*)d_in[7];  const float* bv  = (const float*)d_in[8];
    const float* Wqo = (const float*)d_in[9];  const float* bqo = (const float*)d_in[10];
    const float* Wko = (const float*)d_in[11]; const float* bko = (const float*)d_in[12];
    const float* Wqt = (const float*)d_in[13]; const float* bqt = (const float*)d_in[14];
    const float* Wkt = (const float*)d_in[15]; const float* bkt = (const float*)d_in[16];
    const float* Wo  = (const float*)d_in[17]; const float* bo  = (const float*)d_in[18];
    const float* Wlam= (const float*)d_in[19]; const float* blam= (const float*)d_in[20];
    const float* U   = (const float*)d_in[21]; const float* Sv  = (const float*)d_in[22];

    float* out = (float*)d_out_v;
    float* W   = (float*)d_ws;

    short* qpB = (short*)W;
    short* kpB = (short*)(W + 4194304);
    short* vpB = (short*)(W + 8388608);
    float* attn_out = W + 4194304;
    short* TTB = (short*)(W + 12582912);
    short* R1  = (short*)(W + 16777216);
    short* qinB = R1;
    short* kinB = R1 + 4194304;
    short* vinB = R1 + 8388608;
    short* qresB = qinB;  short* kresB = kinB;  short* vtB = vinB;
    short* aoB = kresB;
    short* T1tB = (short*)W;
    short* UB  = (short*)(W + 8388608);
    short* UtB = UB + 262144;
    float* q_om = W + 29360128;
    float* k_om = q_om + 131072;
    float* q_th = k_om + 131072;
    float* k_th = q_th + 131072;
    float* Cq   = k_th + 131072;
    float* Ck   = Cq + 262144;
    float* wbuf = Ck + 262144;
    float* partials = wbuf + 65536;
    short* wsp = (short*)(W + 30475264);
    short* WqB = wsp;
    short* WkB = wsp + 262144;
    short* WvB = wsp + 524288;
    short* WoB = wsp + 786432;

    float* attn = out + ATTN_OFF;
    dim3 blk(256);

    // 0. pre-converts
    wconv_t<<<dim3(8,8,4), blk, 0, stream>>>(Wq, Wk, Wv, Wo, WqB, WkB, WvB, WoB);
    acvt<<<dim3(6144), blk, 0, stream>>>(queries, keys, values, R1);

    // 1. fused QKV projection -> bf16 (EPI 6)
    mgemm<128,128,true,6><<<dim3(4,64,3), blk, 0, stream>>>(
        512, qinB, 512, 0, 0, WqB, 0, 0,
        nullptr, 512, 0, 0,
        bq, bk, bv, nullptr, qpB, 1);

    // 2. fused omega/theta projections + phase tables
    skinny_k<<<dim3(1024,2), blk, 0, stream>>>(queries, keys,
        Wqo, bqo, Wqt, bqt, Wko, bko, Wkt, bkt,
        q_om, q_th, Cq, k_om, k_th, Ck);

    // 3. fused series decomposition
    movavg_all<<<dim3(8,8,48), blk, 0, stream>>>(qpB, kpB, vpB,
        qresB, kresB, vtB, TTB);

    // 3.5 U -> bf16 (both layouts), into now-dead vp region
    uconv<<<dim3(8,8), blk, 0, stream>>>(U, UB, UtB);

    // 4. fused scores+softmax+attn-write+PV (v5: packed scores, 2 waves/SIMD)
    flash_k<<<dim3(8,128), blk, 0, stream>>>(qresB, kresB, vtB, Cq, Ck, attn, attn_out);

    // 5. lambda conv -> w (reads trend^T bf16)
    lamw_k<<<dim3(128), dim3(512), 0, stream>>>(TTB, Wlam, blam, Sv, wbuf);

    // 6. T1t[e][i] = (sum_l trend[l][e] U[l][i]) * w[i] -> bf16 (EPI 4)
    mgemm<64,128,false,4><<<dim3(4,1,128), blk, 0, stream>>>(
        512, TTB, 512, 262144, 32768, UtB, 0, 0,
        nullptr, 512, 262144, 32768,
        nullptr, nullptr, nullptr, wbuf, T1tB, 8);

    // 7. aoB(bf16) = attn_out(f32) + U @ T1  (EPI 5)
    mgemm<128,64,false,5><<<dim3(1,4,128), blk, 0, stream>>>(
        512, UB, 512, 0, 0, T1tB, 262144, 32768,
        attn_out, 512, 262144, 64,
        nullptr, nullptr, nullptr, nullptr, aoB, 8);

    // 8. out projection (EPI 1)
    mgemm<64,128,false,1><<<dim3(4,128,1), blk, 0, stream>>>(
        512, aoB, 512, 0, 0, WoB, 0, 0,
        out, 512, 0, 0,
        bo, nullptr, nullptr, nullptr, nullptr, 1);

    // 9. penalties
    pen1_k<<<dim3(256), blk, 0, stream>>>(q_om, k_om, q_th, k_th, partials);
    pen2_k<<<dim3(1), blk, 0, stream>>>(partials, out + OM_OFF, out + TH_OFF);
}